// Round 6
// baseline (974.018 us; speedup 1.0000x reference)
//
#include <hip/hip_runtime.h>

// TPF encoder, MFMA fp16, CSR aggregation, wave-independent + DIRECT A-frag loads.
//
// r5 finding: barrier removal changed nothing; per-wave ~92K cy elapsed vs ~8K
// issue -> pure latency starvation at 4 waves/SIMD (LDS-capped). This version
// shrinks LDS 4x by loading GEMM A-fragments DIRECTLY from global (lane(n15,q)
// needs row n15, k=kb*32+q*8..+8 = one 16B load; fp32 inputs via 2xfloat4+cvt,
// same f2h rounding -> identical numerics). Only f1/f2/agg handoffs use LDS:
// 16x136 fp16/wave = 4.35KB -> 17.4KB/block, 9 blocks/CU; launch_bounds(256,6)
// -> 24 waves/CU (75%) vs 43%.
// PROBES (diagnostic, half of level-2, outputs overwritten by real dispatch):
//   MODE1 = sequential gather (no randomness), MODE2 = bf=af (no weight loads).
// Carried: CSR sort-by-dst, conv_h fp16 h-table, packed weights Wp[kb][n][kk].

#define D   128
#define TE  64    // rows per block = 4 waves x 16 rows
#define BS  136   // handoff buffer row stride (halfwords)
#define XS  264   // legacy kernels' stride

typedef float  f32x4 __attribute__((ext_vector_type(4)));
typedef _Float16 f16x8 __attribute__((ext_vector_type(8)));

__device__ __forceinline__ unsigned short f2h(float f) {
    union { _Float16 h; unsigned short u; } x;
    x.h = (_Float16)f;
    return x.u;
}

__device__ __forceinline__ f16x8 h8zero() {
    f16x8 r;
#pragma unroll
    for (int i = 0; i < 8; ++i) r[i] = (_Float16)0.f;
    return r;
}

__device__ __forceinline__ f16x8 cvt8(float4 a, float4 b) {
    f16x8 r;
    r[0] = (_Float16)a.x; r[1] = (_Float16)a.y; r[2] = (_Float16)a.z; r[3] = (_Float16)a.w;
    r[4] = (_Float16)b.x; r[5] = (_Float16)b.y; r[6] = (_Float16)b.z; r[7] = (_Float16)b.w;
    return r;
}

// ---- weight pack: Wp[kb*4096 + n*32 + kk] = fp16(W[kb*32+kk][n]) per matrix,level ----
__global__ __launch_bounds__(256) void pack_w(
    const float* __restrict__ brW1, const float* __restrict__ brW2,
    const float* __restrict__ sW1,  const float* __restrict__ sW2,
    const float* __restrict__ hW,   unsigned short* __restrict__ Wp)
{
    int p = blockIdx.x * 256 + threadIdx.x;   // 0 .. 262143
    const float* src; int off, K;
    if (p < 65536)       { src = brW1; off = 0;      K = 256; }
    else if (p < 98304)  { src = brW2; off = 65536;  K = 128; }
    else if (p < 163840) { src = sW1;  off = 98304;  K = 256; }
    else if (p < 196608) { src = sW2;  off = 163840; K = 128; }
    else                 { src = hW;   off = 196608; K = 256; }
    int q = p - off, lvl, r;
    if (K == 256) { lvl = q >> 15; r = q & 32767; }
    else          { lvl = q >> 14; r = q & 16383; }
    int kb = r >> 12, n = (r >> 5) & 127, kk = r & 31;
    Wp[p] = f2h(src[(size_t)lvl * K * 128 + (size_t)(kb * 32 + kk) * 128 + n]);
}

// ---- h2 fp32 -> fp16 streaming conversion ----
__global__ __launch_bounds__(256) void conv_h(
    const float* __restrict__ in, unsigned short* __restrict__ out, long n)
{
    long i = (long)blockIdx.x * 256 + threadIdx.x;
    long stride = (long)gridDim.x * 256;
    for (; i < n; i += stride) {
        float4 a = ((const float4*)in)[i * 2];
        float4 b = ((const float4*)in)[i * 2 + 1];
        ushort4 o1, o2;
        o1.x = f2h(a.x); o1.y = f2h(a.y); o1.z = f2h(a.z); o1.w = f2h(a.w);
        o2.x = f2h(b.x); o2.y = f2h(b.y); o2.z = f2h(b.z); o2.w = f2h(b.w);
        ((ushort4*)out)[i * 2]     = o1;
        ((ushort4*)out)[i * 2 + 1] = o2;
    }
}

// ================= CSR build =================

__global__ __launch_bounds__(256) void csr_hist(
    const int* __restrict__ dA, int EA, const int* __restrict__ dB, int EB,
    int* __restrict__ cnt, int AOFFv)
{
    int i = blockIdx.x * 256 + threadIdx.x;
    if (i < EA)               atomicAdd(cnt + dA[i], 1);
    else if (i - EA < EB)     atomicAdd(cnt + AOFFv + dB[i - EA], 1);
}

__global__ __launch_bounds__(256) void csr_scanA(
    const int* __restrict__ cnt, int* __restrict__ inc, int* __restrict__ bsum,
    int nbA, int AOFFv)
{
    __shared__ int lds[256];
    int b = blockIdx.x, t = threadIdx.x;
    int lb, ebase, bs;
    if (b < nbA) { lb = b;       ebase = 0;     bs = lb; }
    else         { lb = b - nbA; ebase = AOFFv; bs = 128 + lb; }
    int idx = ebase + lb * 1024 + t * 4;
    int s0 = cnt[idx], s1 = cnt[idx + 1], s2 = cnt[idx + 2], s3 = cnt[idx + 3];
    int p1 = s0 + s1, p2 = p1 + s2, p3 = p2 + s3;
    lds[t] = p3; __syncthreads();
#pragma unroll
    for (int o = 1; o < 256; o <<= 1) {
        int v = (t >= o) ? lds[t - o] : 0;
        __syncthreads();
        lds[t] += v;
        __syncthreads();
    }
    int ex = lds[t] - p3;
    inc[idx] = ex + s0; inc[idx + 1] = ex + p1; inc[idx + 2] = ex + p2; inc[idx + 3] = ex + p3;
    if (t == 255) bsum[bs] = lds[255];
}

__global__ __launch_bounds__(256) void csr_scanB(int* __restrict__ bsum, int nbA, int nbB)
{
    __shared__ int lds[256];
    int t = threadIdx.x, seg = t >> 7, i = t & 127;
    int n = seg ? nbB : nbA;
    lds[t] = (i < n) ? bsum[t] : 0;
    __syncthreads();
#pragma unroll
    for (int o = 1; o < 128; o <<= 1) {
        int v = (i >= o) ? lds[t - o] : 0;
        __syncthreads();
        lds[t] += v;
        __syncthreads();
    }
    if (i < n) bsum[t] = lds[t];
}

__global__ __launch_bounds__(256) void csr_scanC(
    const int* __restrict__ cnt, int* __restrict__ inc, const int* __restrict__ bsum,
    int* __restrict__ cursor, int nbA, int AOFFv)
{
    int b = blockIdx.x, t = threadIdx.x;
    int lb, ebase, bs;
    if (b < nbA) { lb = b;       ebase = 0;     bs = lb; }
    else         { lb = b - nbA; ebase = AOFFv; bs = 128 + lb; }
    int carry = (lb > 0) ? bsum[bs - 1] : 0;
    int idx = ebase + lb * 1024 + t * 4;
#pragma unroll
    for (int j = 0; j < 4; ++j) {
        int v = inc[idx + j] + carry;
        inc[idx + j] = v;
        cursor[idx + j] = v - cnt[idx + j];
    }
}

__global__ __launch_bounds__(256) void csr_pos(
    const int* __restrict__ dA, int EA, const int* __restrict__ dB, int EB,
    int* __restrict__ cursor, int* __restrict__ posA, int* __restrict__ posB, int AOFFv)
{
    int i = blockIdx.x * 256 + threadIdx.x;
    if (i < EA)           posA[i] = atomicAdd(cursor + dA[i], 1);
    else if (i - EA < EB) posB[i - EA] = atomicAdd(cursor + AOFFv + dB[i - EA], 1);
}

// ================= wave-independent MLP (direct A-frag) =================

// bias + LayerNorm + relu, fully in-register
__device__ __forceinline__ void ln_relu_wv(f32x4 acc[8],
    const float* __restrict__ b, const float* __restrict__ g, const float* __restrict__ be,
    int n15)
{
#pragma unroll
    for (int ct = 0; ct < 8; ++ct) {
        float bb = b[ct * 16 + n15];
#pragma unroll
        for (int r = 0; r < 4; ++r) acc[ct][r] += bb;
    }
    float sum[4], ss[4];
#pragma unroll
    for (int r = 0; r < 4; ++r) {
        float s = 0.f, s2 = 0.f;
#pragma unroll
        for (int ct = 0; ct < 8; ++ct) { s += acc[ct][r]; s2 += acc[ct][r] * acc[ct][r]; }
        sum[r] = s; ss[r] = s2;
    }
#pragma unroll
    for (int off = 1; off < 16; off <<= 1) {
#pragma unroll
        for (int r = 0; r < 4; ++r) {
            sum[r] += __shfl_xor(sum[r], off, 64);
            ss[r]  += __shfl_xor(ss[r],  off, 64);
        }
    }
#pragma unroll
    for (int ct = 0; ct < 8; ++ct) {
        float gg = g[ct * 16 + n15], bb = be[ct * 16 + n15];
#pragma unroll
        for (int r = 0; r < 4; ++r) {
            float mean = sum[r] * (1.f / 128.f);
            float var  = ss[r] * (1.f / 128.f) - mean * mean;
            float rstd = rsqrtf(var + 1e-5f);
            acc[ct][r] = fmaxf((acc[ct][r] - mean) * rstd * gg + bb, 0.f);
        }
    }
}

// MODE: 0 = real, 1 = sequential gather probe, 2 = no-weight probe (bf = af)
template<int MODE>
__global__ __launch_bounds__(256, 6) void edge_mlp_dg(
    const unsigned short* __restrict__ hsrc, const float* __restrict__ bond,
    const int* __restrict__ src, const int* __restrict__ dstpos,
    const unsigned short* __restrict__ Wp1, const unsigned short* __restrict__ Wp2,
    const float* __restrict__ b1, const float* __restrict__ g1, const float* __restrict__ be1,
    const float* __restrict__ b2, const float* __restrict__ g2, const float* __restrict__ be2,
    unsigned short* __restrict__ ebh, int E)
{
    __shared__ unsigned short s_f[4 * 16 * BS];
    int t = threadIdx.x, w = t >> 6, lane = t & 63;
    int n15 = lane & 15, q = lane >> 4;
    int eb = blockIdx.x * TE + w * 16;
    unsigned short* buf = s_f + w * 16 * BS;

    int rA = eb + n15;
    bool vA = rA < E;
    int sv;
    if (MODE == 1) sv = vA ? rA : 0;
    else           sv = vA ? src[rA] : 0;

    f32x4 acc[8];
    f32x4 zero = {0.f, 0.f, 0.f, 0.f};
#pragma unroll
    for (int ct = 0; ct < 8; ++ct) acc[ct] = zero;

    const unsigned short* hp = hsrc + (size_t)sv * 128 + q * 8;
    const float* bp = bond + (size_t)rA * 128 + q * 8;

    // GEMM1 kb 0..3: h part, direct fp16 loads
#pragma unroll
    for (int kb = 0; kb < 4; ++kb) {
        f16x8 af = h8zero();
        if (vA) af = *(const f16x8*)(hp + kb * 32);
        const unsigned short* wb = Wp1 + kb * 4096 + q * 8;
#pragma unroll
        for (int ct = 0; ct < 8; ++ct) {
            f16x8 bf = (MODE == 2) ? af : *(const f16x8*)(wb + (ct * 16 + n15) * 32);
            acc[ct] = __builtin_amdgcn_mfma_f32_16x16x32_f16(af, bf, acc[ct], 0, 0, 0);
        }
    }
    // GEMM1 kb 4..7: bond part, direct fp32 loads + cvt
#pragma unroll
    for (int kb = 0; kb < 4; ++kb) {
        f16x8 af = h8zero();
        if (vA) {
            float4 x = *(const float4*)(bp + kb * 32);
            float4 y = *(const float4*)(bp + kb * 32 + 4);
            af = cvt8(x, y);
        }
        const unsigned short* wb = Wp1 + (size_t)(kb + 4) * 4096 + q * 8;
#pragma unroll
        for (int ct = 0; ct < 8; ++ct) {
            f16x8 bf = (MODE == 2) ? af : *(const f16x8*)(wb + (ct * 16 + n15) * 32);
            acc[ct] = __builtin_amdgcn_mfma_f32_16x16x32_f16(af, bf, acc[ct], 0, 0, 0);
        }
    }
    ln_relu_wv(acc, b1, g1, be1, n15);

    // f1 -> buf (wave-synchronous LDS)
#pragma unroll
    for (int ct = 0; ct < 8; ++ct)
#pragma unroll
        for (int r = 0; r < 4; ++r)
            buf[(q * 4 + r) * BS + ct * 16 + n15] = f2h(acc[ct][r]);

    // GEMM2 from buf
#pragma unroll
    for (int ct = 0; ct < 8; ++ct) acc[ct] = zero;
#pragma unroll
    for (int kb = 0; kb < 4; ++kb) {
        f16x8 af = *(const f16x8*)(buf + n15 * BS + kb * 32 + q * 8);
        const unsigned short* wb = Wp2 + (size_t)kb * 4096 + q * 8;
#pragma unroll
        for (int ct = 0; ct < 8; ++ct) {
            f16x8 bf = (MODE == 2) ? af : *(const f16x8*)(wb + (ct * 16 + n15) * 32);
            acc[ct] = __builtin_amdgcn_mfma_f32_16x16x32_f16(af, bf, acc[ct], 0, 0, 0);
        }
    }
    ln_relu_wv(acc, b2, g2, be2, n15);

    // f2 -> buf (after GEMM2 reads; same-wave LDS order preserved)
#pragma unroll
    for (int ct = 0; ct < 8; ++ct)
#pragma unroll
        for (int r = 0; r < 4; ++r)
            buf[(q * 4 + r) * BS + ct * 16 + n15] = f2h(acc[ct][r]);

    // coalesced 256B row stores to dst-sorted slots
#pragma unroll
    for (int j = 0; j < 4; ++j) {
        int row = q + 4 * j;
        int ge = eb + row;
        if (ge < E) {
            int p = dstpos[ge];
            *(uint4*)(ebh + (size_t)p * 128 + n15 * 8) =
                *(const uint4*)(buf + row * BS + n15 * 8);
        }
    }
}

template<bool OUT_F16>
__global__ __launch_bounds__(256, 6) void node_mlp_dg(
    const float* __restrict__ ax,
    const int* __restrict__ inc, const unsigned short* __restrict__ ebh,
    const unsigned short* __restrict__ Wp1, const unsigned short* __restrict__ Wp2,
    const unsigned short* __restrict__ Wp3,
    const float* __restrict__ b1, const float* __restrict__ g1, const float* __restrict__ be1,
    const float* __restrict__ b2, const float* __restrict__ g2, const float* __restrict__ be2,
    const float* __restrict__ b3, const float* __restrict__ g3, const float* __restrict__ be3,
    void* __restrict__ out, int N)
{
    __shared__ unsigned short s_f[4 * 16 * BS];
    int t = threadIdx.x, w = t >> 6, lane = t & 63;
    int n15 = lane & 15, q = lane >> 4;
    int nb = blockIdx.x * TE + w * 16;
    unsigned short* buf = s_f + w * 16 * BS;

    // ---- fused segment-sum (4 lanes/row, 32 cols) -> buf ----
    {
        int r = lane >> 2, s4 = lane & 3;
        int gr = nb + r;
        int jb = 0, je = 0;
        if (gr < N) { je = inc[gr]; jb = (gr == 0) ? 0 : inc[gr - 1]; }
        float a[32];
#pragma unroll
        for (int k = 0; k < 32; ++k) a[k] = 0.f;
        for (int j = jb; j < je; ++j) {
            const unsigned short* rp = ebh + (size_t)j * 128 + s4 * 32;
            f16x8 v0 = *(const f16x8*)rp;
            f16x8 v1 = *(const f16x8*)(rp + 8);
            f16x8 v2 = *(const f16x8*)(rp + 16);
            f16x8 v3 = *(const f16x8*)(rp + 24);
#pragma unroll
            for (int k = 0; k < 8; ++k) {
                a[k]      += (float)v0[k];
                a[8 + k]  += (float)v1[k];
                a[16 + k] += (float)v2[k];
                a[24 + k] += (float)v3[k];
            }
        }
        unsigned short* op = buf + r * BS + s4 * 32;
#pragma unroll
        for (int blk = 0; blk < 4; ++blk) {
            f16x8 h;
#pragma unroll
            for (int k = 0; k < 8; ++k) h[k] = (_Float16)a[blk * 8 + k];
            *(f16x8*)(op + blk * 8) = h;
        }
    }

    int rA = nb + n15;
    bool vA = rA < N;
    const float* ap = ax + (size_t)rA * 128 + q * 8;

    f32x4 acc[8];
    f32x4 zero = {0.f, 0.f, 0.f, 0.f};
#pragma unroll
    for (int ct = 0; ct < 8; ++ct) acc[ct] = zero;

    // GEMM1 kb0..3: ax direct; kb4..7: agg from buf (seg-sum writes precede in wave order)
#pragma unroll
    for (int kb = 0; kb < 4; ++kb) {
        f16x8 af = h8zero();
        if (vA) {
            float4 x = *(const float4*)(ap + kb * 32);
            float4 y = *(const float4*)(ap + kb * 32 + 4);
            af = cvt8(x, y);
        }
        const unsigned short* wb = Wp1 + (size_t)kb * 4096 + q * 8;
#pragma unroll
        for (int ct = 0; ct < 8; ++ct) {
            f16x8 bf = *(const f16x8*)(wb + (ct * 16 + n15) * 32);
            acc[ct] = __builtin_amdgcn_mfma_f32_16x16x32_f16(af, bf, acc[ct], 0, 0, 0);
        }
    }
#pragma unroll
    for (int kb = 0; kb < 4; ++kb) {
        f16x8 af = *(const f16x8*)(buf + n15 * BS + kb * 32 + q * 8);
        const unsigned short* wb = Wp1 + (size_t)(kb + 4) * 4096 + q * 8;
#pragma unroll
        for (int ct = 0; ct < 8; ++ct) {
            f16x8 bf = *(const f16x8*)(wb + (ct * 16 + n15) * 32);
            acc[ct] = __builtin_amdgcn_mfma_f32_16x16x32_f16(af, bf, acc[ct], 0, 0, 0);
        }
    }
    ln_relu_wv(acc, b1, g1, be1, n15);

    // f1 -> buf
#pragma unroll
    for (int ct = 0; ct < 8; ++ct)
#pragma unroll
        for (int r = 0; r < 4; ++r)
            buf[(q * 4 + r) * BS + ct * 16 + n15] = f2h(acc[ct][r]);

    // GEMM2 from buf
#pragma unroll
    for (int ct = 0; ct < 8; ++ct) acc[ct] = zero;
#pragma unroll
    for (int kb = 0; kb < 4; ++kb) {
        f16x8 af = *(const f16x8*)(buf + n15 * BS + kb * 32 + q * 8);
        const unsigned short* wb = Wp2 + (size_t)kb * 4096 + q * 8;
#pragma unroll
        for (int ct = 0; ct < 8; ++ct) {
            f16x8 bf = *(const f16x8*)(wb + (ct * 16 + n15) * 32);
            acc[ct] = __builtin_amdgcn_mfma_f32_16x16x32_f16(af, bf, acc[ct], 0, 0, 0);
        }
    }
    ln_relu_wv(acc, b2, g2, be2, n15);

    // f2 -> buf; th = [ax | f2]
#pragma unroll
    for (int ct = 0; ct < 8; ++ct)
#pragma unroll
        for (int r = 0; r < 4; ++r)
            buf[(q * 4 + r) * BS + ct * 16 + n15] = f2h(acc[ct][r]);

    // GEMM3: kb0..3 ax direct, kb4..7 f2 from buf
#pragma unroll
    for (int ct = 0; ct < 8; ++ct) acc[ct] = zero;
#pragma unroll
    for (int kb = 0; kb < 4; ++kb) {
        f16x8 af = h8zero();
        if (vA) {
            float4 x = *(const float4*)(ap + kb * 32);
            float4 y = *(const float4*)(ap + kb * 32 + 4);
            af = cvt8(x, y);
        }
        const unsigned short* wb = Wp3 + (size_t)kb * 4096 + q * 8;
#pragma unroll
        for (int ct = 0; ct < 8; ++ct) {
            f16x8 bf = *(const f16x8*)(wb + (ct * 16 + n15) * 32);
            acc[ct] = __builtin_amdgcn_mfma_f32_16x16x32_f16(af, bf, acc[ct], 0, 0, 0);
        }
    }
#pragma unroll
    for (int kb = 0; kb < 4; ++kb) {
        f16x8 af = *(const f16x8*)(buf + n15 * BS + kb * 32 + q * 8);
        const unsigned short* wb = Wp3 + (size_t)(kb + 4) * 4096 + q * 8;
#pragma unroll
        for (int ct = 0; ct < 8; ++ct) {
            f16x8 bf = *(const f16x8*)(wb + (ct * 16 + n15) * 32);
            acc[ct] = __builtin_amdgcn_mfma_f32_16x16x32_f16(af, bf, acc[ct], 0, 0, 0);
        }
    }
    ln_relu_wv(acc, b3, g3, be3, n15);

    if (OUT_F16) {
#pragma unroll
        for (int ct = 0; ct < 8; ++ct)
#pragma unroll
            for (int r = 0; r < 4; ++r)
                buf[(q * 4 + r) * BS + ct * 16 + n15] = f2h(acc[ct][r]);
#pragma unroll
        for (int j = 0; j < 4; ++j) {
            int row = q + 4 * j;
            int gr = nb + row;
            if (gr < N)
                *(uint4*)((unsigned short*)out + (size_t)gr * D + n15 * 8) =
                    *(const uint4*)(buf + row * BS + n15 * 8);
        }
    } else {
#pragma unroll
        for (int ct = 0; ct < 8; ++ct)
#pragma unroll
            for (int r = 0; r < 4; ++r) {
                int gr = nb + q * 4 + r;
                if (gr < N)
                    ((float*)out)[(size_t)gr * D + ct * 16 + n15] = acc[ct][r];
            }
    }
}

// ================= legacy kernels (fallback tiers only) =================

template<int KB>
__device__ __forceinline__ void gemm_f16(const unsigned short* s_in, int stride,
    const unsigned short* __restrict__ Wp, int rb, int cb, int n15, int q, f32x4 acc[2][4])
{
    f32x4 zero = {0.f, 0.f, 0.f, 0.f};
#pragma unroll
    for (int m = 0; m < 2; ++m)
#pragma unroll
        for (int ct = 0; ct < 4; ++ct) acc[m][ct] = zero;
#pragma unroll
    for (int kb = 0; kb < KB; ++kb) {
        f16x8 af0 = *(const f16x8*)(s_in + (rb + n15) * stride + kb * 32 + q * 8);
        f16x8 af1 = *(const f16x8*)(s_in + (rb + 16 + n15) * stride + kb * 32 + q * 8);
        const unsigned short* wb = Wp + (size_t)kb * 4096 + q * 8;
#pragma unroll
        for (int ct = 0; ct < 4; ++ct) {
            f16x8 bf = *(const f16x8*)(wb + (cb + ct * 16 + n15) * 32);
            acc[0][ct] = __builtin_amdgcn_mfma_f32_16x16x32_f16(af0, bf, acc[0][ct], 0, 0, 0);
            acc[1][ct] = __builtin_amdgcn_mfma_f32_16x16x32_f16(af1, bf, acc[1][ct], 0, 0, 0);
        }
    }
}

__device__ __forceinline__ void ln_relu(f32x4 acc[2][4],
    const float* __restrict__ b, const float* __restrict__ g, const float* __restrict__ be,
    float* s_red, float* s_ms, int rb, int cb, int n15, int q, int wcol, int t)
{
#pragma unroll
    for (int ct = 0; ct < 4; ++ct) {
        float bb = b[cb + ct * 16 + n15];
#pragma unroll
        for (int m = 0; m < 2; ++m)
#pragma unroll
            for (int r = 0; r < 4; ++r) acc[m][ct][r] += bb;
    }
    float sum[2][4], ss[2][4];
#pragma unroll
    for (int m = 0; m < 2; ++m)
#pragma unroll
        for (int r = 0; r < 4; ++r) {
            sum[m][r] = acc[m][0][r] + acc[m][1][r] + acc[m][2][r] + acc[m][3][r];
            ss[m][r]  = acc[m][0][r]*acc[m][0][r] + acc[m][1][r]*acc[m][1][r]
                      + acc[m][2][r]*acc[m][2][r] + acc[m][3][r]*acc[m][3][r];
        }
#pragma unroll
    for (int off = 1; off < 16; off <<= 1) {
#pragma unroll
        for (int m = 0; m < 2; ++m)
#pragma unroll
            for (int r = 0; r < 4; ++r) {
                sum[m][r] += __shfl_xor(sum[m][r], off, 64);
                ss[m][r]  += __shfl_xor(ss[m][r],  off, 64);
            }
    }
    if (n15 == 0) {
#pragma unroll
        for (int m = 0; m < 2; ++m)
#pragma unroll
            for (int r = 0; r < 4; ++r) {
                int row = rb + m * 16 + q * 4 + r;
                s_red[row * 4 + wcol * 2 + 0] = sum[m][r];
                s_red[row * 4 + wcol * 2 + 1] = ss[m][r];
            }
    }
    __syncthreads();
    if (t < TE) {
        float sm = s_red[t * 4 + 0] + s_red[t * 4 + 2];
        float sq = s_red[t * 4 + 1] + s_red[t * 4 + 3];
        float mean = sm * (1.f / 128.f);
        float var  = sq * (1.f / 128.f) - mean * mean;
        s_ms[t * 2 + 0] = mean;
        s_ms[t * 2 + 1] = rsqrtf(var + 1e-5f);
    }
    __syncthreads();
#pragma unroll
    for (int ct = 0; ct < 4; ++ct) {
        float gg = g[cb + ct * 16 + n15], bb = be[cb + ct * 16 + n15];
#pragma unroll
        for (int m = 0; m < 2; ++m)
#pragma unroll
            for (int r = 0; r < 4; ++r) {
                int row = rb + m * 16 + q * 4 + r;
                float v = (acc[m][ct][r] - s_ms[row * 2 + 0]) * s_ms[row * 2 + 1] * gg + bb;
                acc[m][ct][r] = fmaxf(v, 0.f);
            }
    }
}

template<bool HBF16, bool CSR>
__global__ __launch_bounds__(256, 4) void edge_mlp(
    const void* __restrict__ hsrc, const float* __restrict__ bond,
    const int* __restrict__ src, const int* __restrict__ dstpos,
    const unsigned short* __restrict__ Wp1, const unsigned short* __restrict__ Wp2,
    const float* __restrict__ b1, const float* __restrict__ g1, const float* __restrict__ be1,
    const float* __restrict__ b2, const float* __restrict__ g2, const float* __restrict__ be2,
    float* __restrict__ agg, unsigned short* __restrict__ ebh, int E)
{
    __shared__ unsigned short s_x[TE * XS];
    __shared__ float s_red[TE * 4];
    __shared__ float s_ms[TE * 2];
    __shared__ int s_src[TE], s_idx[TE];
    unsigned short* s_y = s_x + 128;

    int t = threadIdx.x, eb = blockIdx.x * TE;
    if (t < TE) {
        int ge = eb + t;
        s_src[t] = (ge < E) ? src[ge] : -1;
        s_idx[t] = (ge < E) ? dstpos[ge] : -1;
    }
    __syncthreads();

    if (HBF16) {
        const unsigned short* hp = (const unsigned short*)hsrc;
        for (int c = t; c < TE * 16; c += 256) {
            int row = c >> 4, k8 = c & 15;
            int s = s_src[row];
            uint4 v = make_uint4(0, 0, 0, 0);
            if (s >= 0) v = *(const uint4*)(hp + (size_t)s * 128 + k8 * 8);
            *(uint4*)(s_x + row * XS + k8 * 8) = v;
        }
    } else {
        const float* hp = (const float*)hsrc;
        for (int c = t; c < TE * 32; c += 256) {
            int row = c >> 5, k4 = c & 31;
            int s = s_src[row];
            float4 v = make_float4(0, 0, 0, 0);
            if (s >= 0) v = *(const float4*)(hp + (size_t)s * 128 + k4 * 4);
            ushort4 o; o.x = f2h(v.x); o.y = f2h(v.y); o.z = f2h(v.z); o.w = f2h(v.w);
            *(ushort4*)(s_x + row * XS + k4 * 4) = o;
        }
    }
    for (int c = t; c < TE * 32; c += 256) {
        int row = c >> 5, k4 = c & 31;
        int ge = eb + row;
        float4 v = make_float4(0, 0, 0, 0);
        if (ge < E) v = *(const float4*)(bond + (size_t)ge * 128 + k4 * 4);
        ushort4 o; o.x = f2h(v.x); o.y = f2h(v.y); o.z = f2h(v.z); o.w = f2h(v.w);
        *(ushort4*)(s_x + row * XS + 128 + k4 * 4) = o;
    }
    __syncthreads();

    int l = t & 63, w = t >> 6;
    int n15 = l & 15, q = l >> 4;
    int rb = (w & 1) * 32, cb = (w >> 1) * 64, wcol = w >> 1;

    f32x4 acc[2][4];
    gemm_f16<8>(s_x, XS, Wp1, rb, cb, n15, q, acc);
    ln_relu(acc, b1, g1, be1, s_red, s_ms, rb, cb, n15, q, wcol, t);
#pragma unroll
    for (int m = 0; m < 2; ++m)
#pragma unroll
        for (int ct = 0; ct < 4; ++ct)
#pragma unroll
            for (int r = 0; r < 4; ++r)
                s_y[(rb + m * 16 + q * 4 + r) * XS + cb + ct * 16 + n15] = f2h(acc[m][ct][r]);
    __syncthreads();
    gemm_f16<4>(s_y, XS, Wp2, rb, cb, n15, q, acc);
    ln_relu(acc, b2, g2, be2, s_red, s_ms, rb, cb, n15, q, wcol, t);

    if (CSR) {
#pragma unroll
        for (int m = 0; m < 2; ++m)
#pragma unroll
            for (int ct = 0; ct < 4; ++ct)
#pragma unroll
                for (int r = 0; r < 4; ++r)
                    s_x[(rb + m * 16 + q * 4 + r) * XS + cb + ct * 16 + n15] = f2h(acc[m][ct][r]);
        __syncthreads();
        for (int c = t; c < TE * 16; c += 256) {
            int row = c >> 4, k8 = c & 15;
            int p = s_idx[row];
            if (p >= 0)
                *(uint4*)(ebh + (size_t)p * 128 + k8 * 8) =
                    *(const uint4*)(s_x + row * XS + k8 * 8);
        }
    } else {
#pragma unroll
        for (int m = 0; m < 2; ++m)
#pragma unroll
            for (int ct = 0; ct < 4; ++ct)
#pragma unroll
                for (int r = 0; r < 4; ++r) {
                    int row = rb + m * 16 + q * 4 + r;
                    int gd = s_idx[row];
                    if (gd >= 0)
                        atomicAdd(agg + (size_t)gd * D + cb + ct * 16 + n15, acc[m][ct][r]);
                }
    }
}

template<bool OUT_F16, bool CSR>
__global__ __launch_bounds__(256, 4) void node_mlp(
    const float* __restrict__ ax, const float* __restrict__ agg,
    const int* __restrict__ inc, const unsigned short* __restrict__ ebh,
    const unsigned short* __restrict__ Wp1, const unsigned short* __restrict__ Wp2,
    const unsigned short* __restrict__ Wp3,
    const float* __restrict__ b1, const float* __restrict__ g1, const float* __restrict__ be1,
    const float* __restrict__ b2, const float* __restrict__ g2, const float* __restrict__ be2,
    const float* __restrict__ b3, const float* __restrict__ g3, const float* __restrict__ be3,
    void* __restrict__ out, int N)
{
    __shared__ unsigned short s_x[TE * XS];
    __shared__ float s_red[TE * 4];
    __shared__ float s_ms[TE * 2];
    __shared__ int s_beg[TE], s_end[TE];
    unsigned short* s_y = s_x + 128;

    int t = threadIdx.x, nb = blockIdx.x * TE;

    if (CSR && t < TE) {
        int gr = nb + t, b0 = 0, e0 = 0;
        if (gr < N) { e0 = inc[gr]; b0 = (gr == 0) ? 0 : inc[gr - 1]; }
        s_beg[t] = b0; s_end[t] = e0;
    }

    for (int c = t; c < TE * 32; c += 256) {
        int row = c >> 5, k4 = c & 31;
        int gr = nb + row;
        float4 v = make_float4(0, 0, 0, 0);
        if (gr < N) v = *(const float4*)(ax + (size_t)gr * 128 + k4 * 4);
        ushort4 o; o.x = f2h(v.x); o.y = f2h(v.y); o.z = f2h(v.z); o.w = f2h(v.w);
        *(ushort4*)(s_x + row * XS + k4 * 4) = o;
    }

    if (CSR) {
        __syncthreads();
        int r = t >> 2, s4 = t & 3;
        float a[32];
#pragma unroll
        for (int k = 0; k < 32; ++k) a[k] = 0.f;
        int jb = s_beg[r], je = s_end[r];
        for (int j = jb; j < je; ++j) {
            const unsigned short* rp = ebh + (size_t)j * 128 + s4 * 32;
            f16x8 v0 = *(const f16x8*)rp;
            f16x8 v1 = *(const f16x8*)(rp + 8);
            f16x8 v2 = *(const f16x8*)(rp + 16);
            f16x8 v3 = *(const f16x8*)(rp + 24);
#pragma unroll
            for (int k = 0; k < 8; ++k) {
                a[k]      += (float)v0[k];
                a[8 + k]  += (float)v1[k];
                a[16 + k] += (float)v2[k];
                a[24 + k] += (float)v3[k];
            }
        }
        unsigned short* op = s_x + r * XS + 128 + s4 * 32;
#pragma unroll
        for (int blk = 0; blk < 4; ++blk) {
            f16x8 h;
#pragma unroll
            for (int k = 0; k < 8; ++k) h[k] = (_Float16)a[blk * 8 + k];
            *(f16x8*)(op + blk * 8) = h;
        }
    } else {
        for (int c = t; c < TE * 32; c += 256) {
            int row = c >> 5, k4 = c & 31;
            int gr = nb + row;
            float4 v = make_float4(0, 0, 0, 0);
            if (gr < N) v = *(const float4*)(agg + (size_t)gr * 128 + k4 * 4);
            ushort4 o; o.x = f2h(v.x); o.y = f2h(v.y); o.z = f2h(v.z); o.w = f2h(v.w);
            *(ushort4*)(s_x + row * XS + 128 + k4 * 4) = o;
        }
    }
    __syncthreads();

    int l = t & 63, w = t >> 6;
    int n15 = l & 15, q = l >> 4;
    int rb = (w & 1) * 32, cb = (w >> 1) * 64, wcol = w >> 1;

    f32x4 acc[2][4];
    gemm_f16<8>(s_x, XS, Wp1, rb, cb, n15, q, acc);
    ln_relu(acc, b1, g1, be1, s_red, s_ms, rb, cb, n15, q, wcol, t);
#pragma unroll
    for (int m = 0; m < 2; ++m)
#pragma unroll
        for (int ct = 0; ct < 4; ++ct)
#pragma unroll
            for (int r = 0; r < 4; ++r)
                s_y[(rb + m * 16 + q * 4 + r) * XS + cb + ct * 16 + n15] = f2h(acc[m][ct][r]);
    __syncthreads();
    gemm_f16<4>(s_y, XS, Wp2, rb, cb, n15, q, acc);
    ln_relu(acc, b2, g2, be2, s_red, s_ms, rb, cb, n15, q, wcol, t);
#pragma unroll
    for (int m = 0; m < 2; ++m)
#pragma unroll
        for (int ct = 0; ct < 4; ++ct)
#pragma unroll
            for (int r = 0; r < 4; ++r)
                s_x[(rb + m * 16 + q * 4 + r) * XS + 128 + cb + ct * 16 + n15] = f2h(acc[m][ct][r]);
    __syncthreads();
    gemm_f16<8>(s_x, XS, Wp3, rb, cb, n15, q, acc);
    ln_relu(acc, b3, g3, be3, s_red, s_ms, rb, cb, n15, q, wcol, t);

#pragma unroll
    for (int m = 0; m < 2; ++m)
#pragma unroll
        for (int ct = 0; ct < 4; ++ct)
#pragma unroll
            for (int r = 0; r < 4; ++r) {
                int row = rb + m * 16 + q * 4 + r;
                int gr = nb + row;
                int col = cb + ct * 16 + n15;
                if (gr < N) {
                    if (OUT_F16)
                        ((unsigned short*)out)[(size_t)gr * D + col] = f2h(acc[m][ct][r]);
                    else
                        ((float*)out)[(size_t)gr * D + col] = acc[m][ct][r];
                }
            }
}

extern "C" void kernel_launch(void* const* d_in, const int* in_sizes, int n_in,
                              void* d_out, int out_size, void* d_ws, size_t ws_size,
                              hipStream_t stream)
{
    const float* h2   = (const float*)d_in[0];
    const float* ax1  = (const float*)d_in[1];
    const float* ax0  = (const float*)d_in[2];
    const float* bx2  = (const float*)d_in[3];
    const float* bx1  = (const float*)d_in[4];
    const float* brW1 = (const float*)d_in[5];
    const float* brb1 = (const float*)d_in[6];
    const float* brg1 = (const float*)d_in[7];
    const float* brbe1= (const float*)d_in[8];
    const float* brW2 = (const float*)d_in[9];
    const float* brb2 = (const float*)d_in[10];
    const float* brg2 = (const float*)d_in[11];
    const float* brbe2= (const float*)d_in[12];
    const float* sW1  = (const float*)d_in[13];
    const float* sb1  = (const float*)d_in[14];
    const float* sg1  = (const float*)d_in[15];
    const float* sbe1 = (const float*)d_in[16];
    const float* sW2  = (const float*)d_in[17];
    const float* sb2  = (const float*)d_in[18];
    const float* sg2  = (const float*)d_in[19];
    const float* sbe2 = (const float*)d_in[20];
    const float* hW   = (const float*)d_in[21];
    const float* hb   = (const float*)d_in[22];
    const float* hg   = (const float*)d_in[23];
    const float* hbe  = (const float*)d_in[24];
    const int*   src2 = (const int*)d_in[25];
    const int*   dst2 = (const int*)d_in[26];
    const int*   src1 = (const int*)d_in[27];
    const int*   dst1 = (const int*)d_in[28];

    int n2 = in_sizes[0] / D;
    int n1 = in_sizes[1] / D;
    int n0 = in_sizes[2] / D;

    unsigned short* Wp = (unsigned short*)d_ws;   // 262144 fp16 = 512 KB

    const unsigned short* pBr1[2] = { Wp + 0,      Wp + 32768 };
    const unsigned short* pBr2[2] = { Wp + 65536,  Wp + 65536  + 16384 };
    const unsigned short* pS1 [2] = { Wp + 98304,  Wp + 98304  + 32768 };
    const unsigned short* pS2 [2] = { Wp + 163840, Wp + 163840 + 16384 };
    const unsigned short* pH  [2] = { Wp + 196608, Wp + 196608 + 32768 };

    // ---- workspace layout ----
    int nbA = (n1 + 1023) / 1024, nbB = (n0 + 1023) / 1024;
    int AOFFv = nbA * 1024;
    size_t AN = (size_t)AOFFv + (size_t)nbB * 1024;
    auto al = [](size_t x) { return (x + 255) & ~(size_t)255; };
    size_t o = 524288;
    size_t cnt_o  = o; o = al(o + AN * 4);
    size_t inc_o  = o; o = al(o + AN * 4);
    size_t cur_o  = o; o = al(o + AN * 4);
    size_t bsum_o = o; o = al(o + 1024);
    size_t posA_o = o; o = al(o + (size_t)n2 * 4);
    size_t posB_o = o; o = al(o + (size_t)n1 * 4);
    size_t h1_o   = o; o = al(o + (size_t)n1 * 256);
    size_t ebh_o  = o; o = al(o + (size_t)n2 * 256);
    size_t o_csr  = o;
    size_t h2h_o  = o; o = al(o + (size_t)n2 * 256);
    size_t o_full = o;
    bool csr_ok = (nbA <= 128) && (nbB <= 128);
    bool tier1 = csr_ok && (ws_size >= o_full);
    bool tier2 = !tier1 && csr_ok && (ws_size >= o_csr);

    pack_w<<<dim3(1024), dim3(256), 0, stream>>>(brW1, brW2, sW1, sW2, hW, Wp);

    int t2e = (n2 + TE - 1) / TE, t1e = (n1 + TE - 1) / TE;
    int t1n = (n1 + TE - 1) / TE, t0n = (n0 + TE - 1) / TE;

    if (tier1 || tier2) {
        int*            cnt    = (int*)((char*)d_ws + cnt_o);
        int*            inc    = (int*)((char*)d_ws + inc_o);
        int*            cursor = (int*)((char*)d_ws + cur_o);
        int*            bsum   = (int*)((char*)d_ws + bsum_o);
        int*            posA   = (int*)((char*)d_ws + posA_o);
        int*            posB   = (int*)((char*)d_ws + posB_o);
        unsigned short* h1     = (unsigned short*)((char*)d_ws + h1_o);
        unsigned short* ebh    = (unsigned short*)((char*)d_ws + ebh_o);
        unsigned short* h2h    = (unsigned short*)((char*)d_ws + h2h_o);

        int EG = (n2 + n1 + 255) / 256;
        hipMemsetAsync(cnt, 0, AN * 4, stream);
        csr_hist <<<dim3(EG),        dim3(256), 0, stream>>>(dst2, n2, dst1, n1, cnt, AOFFv);
        csr_scanA<<<dim3(nbA + nbB), dim3(256), 0, stream>>>(cnt, inc, bsum, nbA, AOFFv);
        csr_scanB<<<dim3(1),         dim3(256), 0, stream>>>(bsum, nbA, nbB);
        csr_scanC<<<dim3(nbA + nbB), dim3(256), 0, stream>>>(cnt, inc, bsum, cursor, nbA, AOFFv);
        csr_pos  <<<dim3(EG),        dim3(256), 0, stream>>>(dst2, n2, dst1, n1, cursor, posA, posB, AOFFv);

        if (tier1) {
            conv_h<<<dim3(2048), dim3(256), 0, stream>>>(h2, h2h, (long)n2 * 16);

            // ---- DIAGNOSTIC PROBES (half of level 2; ebh fully overwritten below) ----
            int Ep = n2 / 2;
            if (Ep > 0) {
                int tpe = (Ep + TE - 1) / TE;
                edge_mlp_dg<1><<<dim3(tpe), dim3(256), 0, stream>>>(   // sequential gather
                    h2h, bx2, src2, posA, pBr1[0], pBr2[0],
                    brb1, brg1, brbe1, brb2, brg2, brbe2, ebh, Ep);
                edge_mlp_dg<2><<<dim3(tpe), dim3(256), 0, stream>>>(   // no weight loads
                    h2h, bx2, src2, posA, pBr1[0], pBr2[0],
                    brb1, brg1, brbe1, brb2, brg2, brbe2, ebh, Ep);
            }

            // ---- iteration 0 (level 2 -> 1) ----
            edge_mlp_dg<0><<<dim3(t2e), dim3(256), 0, stream>>>(
                h2h, bx2, src2, posA, pBr1[0], pBr2[0],
                brb1, brg1, brbe1, brb2, brg2, brbe2, ebh, n2);
            node_mlp_dg<true><<<dim3(t1n), dim3(256), 0, stream>>>(
                ax1, inc, ebh, pS1[0], pS2[0], pH[0],
                sb1, sg1, sbe1, sb2, sg2, sbe2, hb, hg, hbe, h1, n1);

            // ---- iteration 1 (level 1 -> 0) ----
            edge_mlp_dg<0><<<dim3(t1e), dim3(256), 0, stream>>>(
                h1, bx1, src1, posB, pBr1[1], pBr2[1],
                brb1 + D, brg1 + D, brbe1 + D, brb2 + D, brg2 + D, brbe2 + D, ebh, n1);
            node_mlp_dg<false><<<dim3(t0n), dim3(256), 0, stream>>>(
                ax0, inc + AOFFv, ebh, pS1[1], pS2[1], pH[1],
                sb1 + D, sg1 + D, sbe1 + D, sb2 + D, sg2 + D, sbe2 + D,
                hb + D, hg + D, hbe + D, d_out, n0);
        } else {
            edge_mlp<false, true><<<dim3(t2e), dim3(256), 0, stream>>>(
                h2, bx2, src2, posA, pBr1[0], pBr2[0],
                brb1, brg1, brbe1, brb2, brg2, brbe2, nullptr, ebh, n2);
            node_mlp<true, true><<<dim3(t1n), dim3(256), 0, stream>>>(
                ax1, nullptr, inc, ebh, pS1[0], pS2[0], pH[0],
                sb1, sg1, sbe1, sb2, sg2, sbe2, hb, hg, hbe, h1, n1);
            edge_mlp<true, true><<<dim3(t1e), dim3(256), 0, stream>>>(
                h1, bx1, src1, posB, pBr1[1], pBr2[1],
                brb1 + D, brg1 + D, brbe1 + D, brb2 + D, brg2 + D, brbe2 + D, nullptr, ebh, n1);
            node_mlp<false, true><<<dim3(t0n), dim3(256), 0, stream>>>(
                ax0, nullptr, inc + AOFFv, ebh, pS1[1], pS2[1], pH[1],
                sb1 + D, sg1 + D, sbe1 + D, sb2 + D, sg2 + D, sbe2 + D,
                hb + D, hg + D, hbe + D, d_out, n0);
        }
    } else {
        // fallback: atomic-aggregation path
        float*          agg = (float*)((char*)d_ws + 524288);
        unsigned short* h1  = (unsigned short*)(agg + (size_t)n1 * D);

        hipMemsetAsync(agg, 0, (size_t)n1 * D * sizeof(float), stream);
        edge_mlp<false, false><<<dim3(t2e), dim3(256), 0, stream>>>(
            h2, bx2, src2, dst2, pBr1[0], pBr2[0],
            brb1, brg1, brbe1, brb2, brg2, brbe2, agg, nullptr, n2);
        node_mlp<true, false><<<dim3(t1n), dim3(256), 0, stream>>>(
            ax1, agg, nullptr, nullptr, pS1[0], pS2[0], pH[0],
            sb1, sg1, sbe1, sb2, sg2, sbe2, hb, hg, hbe, h1, n1);

        hipMemsetAsync(agg, 0, (size_t)n0 * D * sizeof(float), stream);
        edge_mlp<true, false><<<dim3(t1e), dim3(256), 0, stream>>>(
            h1, bx1, src1, dst1, pBr1[1], pBr2[1],
            brb1 + D, brg1 + D, brbe1 + D, brb2 + D, brg2 + D, brbe2 + D, agg, nullptr, n1);
        node_mlp<false, false><<<dim3(t0n), dim3(256), 0, stream>>>(
            ax0, agg, nullptr, nullptr, pS1[1], pS2[1], pH[1],
            sb1 + D, sg1 + D, sbe1 + D, sb2 + D, sg2 + D, sbe2 + D,
            hb + D, hg + D, hbe + D, d_out, n0);
    }
}

// Round 7
// 854.226 us; speedup vs baseline: 1.1402x; 1.1402x over previous
//
#include <hip/hip_runtime.h>
#include <hip/hip_cooperative_groups.h>

namespace cg = cooperative_groups;

// TPF encoder, MFMA fp16, CSR aggregation (no float atomics), TE=64 tiles.
//
// r1-r6 ablations: occupancy, barriers, tile size, reg-prefetch, gather pattern
// (probe MODE1) and weight loads (probe MODE2) are ALL non-factors for the MLP
// kernels; edge2 has a hard ~187us floor. The unexplained time is in the STREAM:
// ~150-200us never attributable to any dispatch, across 12 dispatches (7 of them
// us-scale setup kernels). This version collapses pack_w + memset + histogram +
// 3-phase scan + position-assign into ONE cooperative kernel (256 blocks,
// grid.sync between phases) -> 5 dispatches total. MLP kernels are the proven
// r3 versions, byte-identical. Runtime fallback if coop launch is refused.

#define D   128
#define TE  64
#define XS  264   // s_x row stride in fp16 elems (s_y lives at +128, same stride)

typedef float  f32x4 __attribute__((ext_vector_type(4)));
typedef _Float16 f16x8 __attribute__((ext_vector_type(8)));

__device__ __forceinline__ unsigned short f2h(float f) {
    union { _Float16 h; unsigned short u; } x;
    x.h = (_Float16)f;
    return x.u;
}

// ---- weight pack element: Wp[kb*4096 + n*32 + kk] = fp16(W[kb*32+kk][n]) ----
__device__ __forceinline__ void pack_one(int p,
    const float* __restrict__ brW1, const float* __restrict__ brW2,
    const float* __restrict__ sW1,  const float* __restrict__ sW2,
    const float* __restrict__ hW,   unsigned short* __restrict__ Wp)
{
    const float* src; int off, K;
    if (p < 65536)       { src = brW1; off = 0;      K = 256; }
    else if (p < 98304)  { src = brW2; off = 65536;  K = 128; }
    else if (p < 163840) { src = sW1;  off = 98304;  K = 256; }
    else if (p < 196608) { src = sW2;  off = 163840; K = 128; }
    else                 { src = hW;   off = 196608; K = 256; }
    int q = p - off, lvl, r;
    if (K == 256) { lvl = q >> 15; r = q & 32767; }
    else          { lvl = q >> 14; r = q & 16383; }
    int kb = r >> 12, n = (r >> 5) & 127, kk = r & 31;
    Wp[p] = f2h(src[(size_t)lvl * K * 128 + (size_t)(kb * 32 + kk) * 128 + n]);
}

__global__ __launch_bounds__(256) void pack_w(
    const float* __restrict__ brW1, const float* __restrict__ brW2,
    const float* __restrict__ sW1,  const float* __restrict__ sW2,
    const float* __restrict__ hW,   unsigned short* __restrict__ Wp)
{
    pack_one(blockIdx.x * 256 + threadIdx.x, brW1, brW2, sW1, sW2, hW, Wp);
}

// ================= fused cooperative setup: pack + zero + hist + scan + pos =================
// grid = 256 blocks x 256 threads (1 block/CU, trivially co-resident).
// Region A blocks: 0..nbA-1; region B blocks: 128..128+nbB-1 (nbA,nbB <= 128).
__global__ __launch_bounds__(256, 2) void csr_coop(
    const float* __restrict__ brW1, const float* __restrict__ brW2,
    const float* __restrict__ sW1,  const float* __restrict__ sW2,
    const float* __restrict__ hW,   unsigned short* __restrict__ Wp,
    const int* __restrict__ dA, int EA, const int* __restrict__ dB, int EB,
    int* __restrict__ cnt, int* __restrict__ inc, int* __restrict__ cursor,
    int* __restrict__ bsum, int* __restrict__ posA, int* __restrict__ posB,
    int AOFFv, int nbA, int nbB, int AN)
{
    cg::grid_group grid = cg::this_grid();
    __shared__ int lds[256];
    int t = threadIdx.x, b = blockIdx.x;
    int gtid = b * 256 + t, gsz = gridDim.x * 256;

    // ---- P0: zero counts + pack weights ----
    for (int i = gtid; i < AN; i += gsz) cnt[i] = 0;
    for (int p = gtid; p < 262144; p += gsz)
        pack_one(p, brW1, brW2, sW1, sW2, hW, Wp);
    grid.sync();

    // ---- P1: histogram ----
    for (int i = gtid; i < EA + EB; i += gsz) {
        if (i < EA) atomicAdd(cnt + dA[i], 1);
        else        atomicAdd(cnt + AOFFv + dB[i - EA], 1);
    }
    grid.sync();

    // ---- P2a: per-chunk (1024) inclusive scan ----
    bool actA = (b < nbA), actB = (b >= 128 && b < 128 + nbB);
    int lb = actA ? b : b - 128;
    int ebase = actA ? 0 : AOFFv;
    int bs = actA ? lb : 128 + lb;
    if (actA || actB) {
        int idx = ebase + lb * 1024 + t * 4;
        int s0 = cnt[idx], s1 = cnt[idx + 1], s2 = cnt[idx + 2], s3 = cnt[idx + 3];
        int p1 = s0 + s1, p2 = p1 + s2, p3 = p2 + s3;
        lds[t] = p3; __syncthreads();
#pragma unroll
        for (int o = 1; o < 256; o <<= 1) {
            int v = (t >= o) ? lds[t - o] : 0;
            __syncthreads();
            lds[t] += v;
            __syncthreads();
        }
        int ex = lds[t] - p3;
        inc[idx] = ex + s0; inc[idx + 1] = ex + p1;
        inc[idx + 2] = ex + p2; inc[idx + 3] = ex + p3;
        if (t == 255) bsum[bs] = lds[255];
    }
    grid.sync();

    // ---- P2b: scan the two bsum regions (block 0) ----
    if (b == 0) {
        int seg = t >> 7, i = t & 127;
        int n = seg ? nbB : nbA;
        lds[t] = (i < n) ? bsum[t] : 0;
        __syncthreads();
#pragma unroll
        for (int o = 1; o < 128; o <<= 1) {
            int v = (i >= o) ? lds[t - o] : 0;
            __syncthreads();
            lds[t] += v;
            __syncthreads();
        }
        if (i < n) bsum[t] = lds[t];
    }
    grid.sync();

    // ---- P2c: add carries -> final inclusive inc; cursor = exclusive start ----
    if (actA || actB) {
        int carry = (lb > 0) ? bsum[bs - 1] : 0;
        int idx = ebase + lb * 1024 + t * 4;
#pragma unroll
        for (int j = 0; j < 4; ++j) {
            int v = inc[idx + j] + carry;
            inc[idx + j] = v;
            cursor[idx + j] = v - cnt[idx + j];
        }
    }
    grid.sync();

    // ---- P3: per-edge sorted position ----
    for (int i = gtid; i < EA + EB; i += gsz) {
        if (i < EA) posA[i] = atomicAdd(cursor + dA[i], 1);
        else        posB[i - EA] = atomicAdd(cursor + AOFFv + dB[i - EA], 1);
    }
}

// ================= fallback multi-dispatch CSR build =================

__global__ __launch_bounds__(256) void csr_hist(
    const int* __restrict__ dA, int EA, const int* __restrict__ dB, int EB,
    int* __restrict__ cnt, int AOFFv)
{
    int i = blockIdx.x * 256 + threadIdx.x;
    if (i < EA)               atomicAdd(cnt + dA[i], 1);
    else if (i - EA < EB)     atomicAdd(cnt + AOFFv + dB[i - EA], 1);
}

__global__ __launch_bounds__(256) void csr_scanA(
    const int* __restrict__ cnt, int* __restrict__ inc, int* __restrict__ bsum,
    int nbA, int AOFFv)
{
    __shared__ int lds[256];
    int b = blockIdx.x, t = threadIdx.x;
    int lb, ebase, bs;
    if (b < nbA) { lb = b;       ebase = 0;     bs = lb; }
    else         { lb = b - nbA; ebase = AOFFv; bs = 128 + lb; }
    int idx = ebase + lb * 1024 + t * 4;
    int s0 = cnt[idx], s1 = cnt[idx + 1], s2 = cnt[idx + 2], s3 = cnt[idx + 3];
    int p1 = s0 + s1, p2 = p1 + s2, p3 = p2 + s3;
    lds[t] = p3; __syncthreads();
#pragma unroll
    for (int o = 1; o < 256; o <<= 1) {
        int v = (t >= o) ? lds[t - o] : 0;
        __syncthreads();
        lds[t] += v;
        __syncthreads();
    }
    int ex = lds[t] - p3;
    inc[idx] = ex + s0; inc[idx + 1] = ex + p1; inc[idx + 2] = ex + p2; inc[idx + 3] = ex + p3;
    if (t == 255) bsum[bs] = lds[255];
}

__global__ __launch_bounds__(256) void csr_scanB(int* __restrict__ bsum, int nbA, int nbB)
{
    __shared__ int lds[256];
    int t = threadIdx.x, seg = t >> 7, i = t & 127;
    int n = seg ? nbB : nbA;
    lds[t] = (i < n) ? bsum[t] : 0;
    __syncthreads();
#pragma unroll
    for (int o = 1; o < 128; o <<= 1) {
        int v = (i >= o) ? lds[t - o] : 0;
        __syncthreads();
        lds[t] += v;
        __syncthreads();
    }
    if (i < n) bsum[t] = lds[t];
}

__global__ __launch_bounds__(256) void csr_scanC(
    const int* __restrict__ cnt, int* __restrict__ inc, const int* __restrict__ bsum,
    int* __restrict__ cursor, int nbA, int AOFFv)
{
    int b = blockIdx.x, t = threadIdx.x;
    int lb, ebase, bs;
    if (b < nbA) { lb = b;       ebase = 0;     bs = lb; }
    else         { lb = b - nbA; ebase = AOFFv; bs = 128 + lb; }
    int carry = (lb > 0) ? bsum[bs - 1] : 0;
    int idx = ebase + lb * 1024 + t * 4;
#pragma unroll
    for (int j = 0; j < 4; ++j) {
        int v = inc[idx + j] + carry;
        inc[idx + j] = v;
        cursor[idx + j] = v - cnt[idx + j];
    }
}

__global__ __launch_bounds__(256) void csr_pos(
    const int* __restrict__ dA, int EA, const int* __restrict__ dB, int EB,
    int* __restrict__ cursor, int* __restrict__ posA, int* __restrict__ posB, int AOFFv)
{
    int i = blockIdx.x * 256 + threadIdx.x;
    if (i < EA)           posA[i] = atomicAdd(cursor + dA[i], 1);
    else if (i - EA < EB) posB[i - EA] = atomicAdd(cursor + AOFFv + dB[i - EA], 1);
}

// ================= MLP kernels (proven r3 versions) =================

// wave tile: 32 rows (rb + m*16 + q*4 + r) x 64 cols (cb + ct*16 + n15)
template<int KB>
__device__ __forceinline__ void gemm_f16(const unsigned short* s_in, int stride,
    const unsigned short* __restrict__ Wp, int rb, int cb, int n15, int q, f32x4 acc[2][4])
{
    f32x4 zero = {0.f, 0.f, 0.f, 0.f};
#pragma unroll
    for (int m = 0; m < 2; ++m)
#pragma unroll
        for (int ct = 0; ct < 4; ++ct) acc[m][ct] = zero;
#pragma unroll
    for (int kb = 0; kb < KB; ++kb) {
        f16x8 af0 = *(const f16x8*)(s_in + (rb + n15) * stride + kb * 32 + q * 8);
        f16x8 af1 = *(const f16x8*)(s_in + (rb + 16 + n15) * stride + kb * 32 + q * 8);
        const unsigned short* wb = Wp + (size_t)kb * 4096 + q * 8;
#pragma unroll
        for (int ct = 0; ct < 4; ++ct) {
            f16x8 bf = *(const f16x8*)(wb + (cb + ct * 16 + n15) * 32);
            acc[0][ct] = __builtin_amdgcn_mfma_f32_16x16x32_f16(af0, bf, acc[0][ct], 0, 0, 0);
            acc[1][ct] = __builtin_amdgcn_mfma_f32_16x16x32_f16(af1, bf, acc[1][ct], 0, 0, 0);
        }
    }
}

__device__ __forceinline__ void ln_relu(f32x4 acc[2][4],
    const float* __restrict__ b, const float* __restrict__ g, const float* __restrict__ be,
    float* s_red, float* s_ms, int rb, int cb, int n15, int q, int wcol, int t)
{
#pragma unroll
    for (int ct = 0; ct < 4; ++ct) {
        float bb = b[cb + ct * 16 + n15];
#pragma unroll
        for (int m = 0; m < 2; ++m)
#pragma unroll
            for (int r = 0; r < 4; ++r) acc[m][ct][r] += bb;
    }
    float sum[2][4], ss[2][4];
#pragma unroll
    for (int m = 0; m < 2; ++m)
#pragma unroll
        for (int r = 0; r < 4; ++r) {
            sum[m][r] = acc[m][0][r] + acc[m][1][r] + acc[m][2][r] + acc[m][3][r];
            ss[m][r]  = acc[m][0][r]*acc[m][0][r] + acc[m][1][r]*acc[m][1][r]
                      + acc[m][2][r]*acc[m][2][r] + acc[m][3][r]*acc[m][3][r];
        }
#pragma unroll
    for (int off = 1; off < 16; off <<= 1) {
#pragma unroll
        for (int m = 0; m < 2; ++m)
#pragma unroll
            for (int r = 0; r < 4; ++r) {
                sum[m][r] += __shfl_xor(sum[m][r], off, 64);
                ss[m][r]  += __shfl_xor(ss[m][r],  off, 64);
            }
    }
    if (n15 == 0) {
#pragma unroll
        for (int m = 0; m < 2; ++m)
#pragma unroll
            for (int r = 0; r < 4; ++r) {
                int row = rb + m * 16 + q * 4 + r;
                s_red[row * 4 + wcol * 2 + 0] = sum[m][r];
                s_red[row * 4 + wcol * 2 + 1] = ss[m][r];
            }
    }
    __syncthreads();
    if (t < TE) {
        float sm = s_red[t * 4 + 0] + s_red[t * 4 + 2];
        float sq = s_red[t * 4 + 1] + s_red[t * 4 + 3];
        float mean = sm * (1.f / 128.f);
        float var  = sq * (1.f / 128.f) - mean * mean;
        s_ms[t * 2 + 0] = mean;
        s_ms[t * 2 + 1] = rsqrtf(var + 1e-5f);
    }
    __syncthreads();
#pragma unroll
    for (int ct = 0; ct < 4; ++ct) {
        float gg = g[cb + ct * 16 + n15], bb = be[cb + ct * 16 + n15];
#pragma unroll
        for (int m = 0; m < 2; ++m)
#pragma unroll
            for (int r = 0; r < 4; ++r) {
                int row = rb + m * 16 + q * 4 + r;
                float v = (acc[m][ct][r] - s_ms[row * 2 + 0]) * s_ms[row * 2 + 1] * gg + bb;
                acc[m][ct][r] = fmaxf(v, 0.f);
            }
    }
}

// CSR: dstpos = pos[] (sorted slot per edge), output to ebh. Fallback: dstpos = dst[], atomics.
template<bool HBF16, bool CSR>
__global__ __launch_bounds__(256, 4) void edge_mlp(
    const void* __restrict__ hsrc, const float* __restrict__ bond,
    const int* __restrict__ src, const int* __restrict__ dstpos,
    const unsigned short* __restrict__ Wp1, const unsigned short* __restrict__ Wp2,
    const float* __restrict__ b1, const float* __restrict__ g1, const float* __restrict__ be1,
    const float* __restrict__ b2, const float* __restrict__ g2, const float* __restrict__ be2,
    float* __restrict__ agg, unsigned short* __restrict__ ebh, int E)
{
    __shared__ unsigned short s_x[TE * XS];
    __shared__ float s_red[TE * 4];
    __shared__ float s_ms[TE * 2];
    __shared__ int s_src[TE], s_idx[TE];
    unsigned short* s_y = s_x + 128;   // aliased f1 buffer (cols 128..255 dead after GEMM1)

    int t = threadIdx.x, eb = blockIdx.x * TE;
    if (t < TE) {
        int ge = eb + t;
        s_src[t] = (ge < E) ? src[ge] : -1;
        s_idx[t] = (ge < E) ? dstpos[ge] : -1;
    }
    __syncthreads();

    if (HBF16) {
        const unsigned short* hp = (const unsigned short*)hsrc;
        for (int c = t; c < TE * 16; c += 256) {
            int row = c >> 4, k8 = c & 15;
            int s = s_src[row];
            uint4 v = make_uint4(0, 0, 0, 0);
            if (s >= 0) v = *(const uint4*)(hp + (size_t)s * 128 + k8 * 8);
            *(uint4*)(s_x + row * XS + k8 * 8) = v;
        }
    } else {
        const float* hp = (const float*)hsrc;
        for (int c = t; c < TE * 32; c += 256) {
            int row = c >> 5, k4 = c & 31;
            int s = s_src[row];
            float4 v = make_float4(0, 0, 0, 0);
            if (s >= 0) v = *(const float4*)(hp + (size_t)s * 128 + k4 * 4);
            ushort4 o; o.x = f2h(v.x); o.y = f2h(v.y); o.z = f2h(v.z); o.w = f2h(v.w);
            *(ushort4*)(s_x + row * XS + k4 * 4) = o;
        }
    }
    for (int c = t; c < TE * 32; c += 256) {   // bond part (always fp32)
        int row = c >> 5, k4 = c & 31;
        int ge = eb + row;
        float4 v = make_float4(0, 0, 0, 0);
        if (ge < E) v = *(const float4*)(bond + (size_t)ge * 128 + k4 * 4);
        ushort4 o; o.x = f2h(v.x); o.y = f2h(v.y); o.z = f2h(v.z); o.w = f2h(v.w);
        *(ushort4*)(s_x + row * XS + 128 + k4 * 4) = o;
    }
    __syncthreads();

    int l = t & 63, w = t >> 6;
    int n15 = l & 15, q = l >> 4;
    int rb = (w & 1) * 32, cb = (w >> 1) * 64, wcol = w >> 1;

    f32x4 acc[2][4];
    gemm_f16<8>(s_x, XS, Wp1, rb, cb, n15, q, acc);
    ln_relu(acc, b1, g1, be1, s_red, s_ms, rb, cb, n15, q, wcol, t);
#pragma unroll
    for (int m = 0; m < 2; ++m)
#pragma unroll
        for (int ct = 0; ct < 4; ++ct)
#pragma unroll
            for (int r = 0; r < 4; ++r)
                s_y[(rb + m * 16 + q * 4 + r) * XS + cb + ct * 16 + n15] = f2h(acc[m][ct][r]);
    __syncthreads();
    gemm_f16<4>(s_y, XS, Wp2, rb, cb, n15, q, acc);
    ln_relu(acc, b2, g2, be2, s_red, s_ms, rb, cb, n15, q, wcol, t);

    if (CSR) {
#pragma unroll
        for (int m = 0; m < 2; ++m)
#pragma unroll
            for (int ct = 0; ct < 4; ++ct)
#pragma unroll
                for (int r = 0; r < 4; ++r)
                    s_x[(rb + m * 16 + q * 4 + r) * XS + cb + ct * 16 + n15] = f2h(acc[m][ct][r]);
        __syncthreads();
        for (int c = t; c < TE * 16; c += 256) {   // coalesced 256B row stores
            int row = c >> 4, k8 = c & 15;
            int p = s_idx[row];
            if (p >= 0)
                *(uint4*)(ebh + (size_t)p * 128 + k8 * 8) =
                    *(const uint4*)(s_x + row * XS + k8 * 8);
        }
    } else {
#pragma unroll
        for (int m = 0; m < 2; ++m)
#pragma unroll
            for (int ct = 0; ct < 4; ++ct)
#pragma unroll
                for (int r = 0; r < 4; ++r) {
                    int row = rb + m * 16 + q * 4 + r;
                    int gd = s_idx[row];
                    if (gd >= 0)
                        atomicAdd(agg + (size_t)gd * D + cb + ct * 16 + n15, acc[m][ct][r]);
                }
    }
}

// CSR: inc = per-node inclusive edge-count scan; ebh = dst-sorted edge rows.
template<bool OUT_F16, bool CSR>
__global__ __launch_bounds__(256, 4) void node_mlp(
    const float* __restrict__ ax, const float* __restrict__ agg,
    const int* __restrict__ inc, const unsigned short* __restrict__ ebh,
    const unsigned short* __restrict__ Wp1, const unsigned short* __restrict__ Wp2,
    const unsigned short* __restrict__ Wp3,
    const float* __restrict__ b1, const float* __restrict__ g1, const float* __restrict__ be1,
    const float* __restrict__ b2, const float* __restrict__ g2, const float* __restrict__ be2,
    const float* __restrict__ b3, const float* __restrict__ g3, const float* __restrict__ be3,
    void* __restrict__ out, int N)
{
    __shared__ unsigned short s_x[TE * XS];
    __shared__ float s_red[TE * 4];
    __shared__ float s_ms[TE * 2];
    __shared__ int s_beg[TE], s_end[TE];
    unsigned short* s_y = s_x + 128;   // aliased f1 buffer

    int t = threadIdx.x, nb = blockIdx.x * TE;

    if (CSR && t < TE) {
        int gr = nb + t, b0 = 0, e0 = 0;
        if (gr < N) { e0 = inc[gr]; b0 = (gr == 0) ? 0 : inc[gr - 1]; }
        s_beg[t] = b0; s_end[t] = e0;
    }

    for (int c = t; c < TE * 32; c += 256) {   // ax part
        int row = c >> 5, k4 = c & 31;
        int gr = nb + row;
        float4 v = make_float4(0, 0, 0, 0);
        if (gr < N) v = *(const float4*)(ax + (size_t)gr * 128 + k4 * 4);
        ushort4 o; o.x = f2h(v.x); o.y = f2h(v.y); o.z = f2h(v.z); o.w = f2h(v.w);
        *(ushort4*)(s_x + row * XS + k4 * 4) = o;
    }

    if (CSR) {
        __syncthreads();   // s_beg/s_end visible
        int r = t >> 2, s4 = t & 3;
        float a[32];
#pragma unroll
        for (int k = 0; k < 32; ++k) a[k] = 0.f;
        int jb = s_beg[r], je = s_end[r];
        for (int j = jb; j < je; ++j) {
            const unsigned short* rp = ebh + (size_t)j * 128 + s4 * 32;
            f16x8 v0 = *(const f16x8*)rp;
            f16x8 v1 = *(const f16x8*)(rp + 8);
            f16x8 v2 = *(const f16x8*)(rp + 16);
            f16x8 v3 = *(const f16x8*)(rp + 24);
#pragma unroll
            for (int k = 0; k < 8; ++k) {
                a[k]      += (float)v0[k];
                a[8 + k]  += (float)v1[k];
                a[16 + k] += (float)v2[k];
                a[24 + k] += (float)v3[k];
            }
        }
        unsigned short* op = s_x + r * XS + 128 + s4 * 32;
#pragma unroll
        for (int blk = 0; blk < 4; ++blk) {
            f16x8 h;
#pragma unroll
            for (int k = 0; k < 8; ++k) h[k] = (_Float16)a[blk * 8 + k];
            *(f16x8*)(op + blk * 8) = h;
        }
    } else {
        for (int c = t; c < TE * 32; c += 256) {   // agg part (fp32 buffer)
            int row = c >> 5, k4 = c & 31;
            int gr = nb + row;
            float4 v = make_float4(0, 0, 0, 0);
            if (gr < N) v = *(const float4*)(agg + (size_t)gr * 128 + k4 * 4);
            ushort4 o; o.x = f2h(v.x); o.y = f2h(v.y); o.z = f2h(v.z); o.w = f2h(v.w);
            *(ushort4*)(s_x + row * XS + 128 + k4 * 4) = o;
        }
    }
    __syncthreads();

    int l = t & 63, w = t >> 6;
    int n15 = l & 15, q = l >> 4;
    int rb = (w & 1) * 32, cb = (w >> 1) * 64, wcol = w >> 1;

    f32x4 acc[2][4];
    gemm_f16<8>(s_x, XS, Wp1, rb, cb, n15, q, acc);
    ln_relu(acc, b1, g1, be1, s_red, s_ms, rb, cb, n15, q, wcol, t);
#pragma unroll
    for (int m = 0; m < 2; ++m)
#pragma unroll
        for (int ct = 0; ct < 4; ++ct)
#pragma unroll
            for (int r = 0; r < 4; ++r)
                s_y[(rb + m * 16 + q * 4 + r) * XS + cb + ct * 16 + n15] = f2h(acc[m][ct][r]);
    __syncthreads();
    gemm_f16<4>(s_y, XS, Wp2, rb, cb, n15, q, acc);
    ln_relu(acc, b2, g2, be2, s_red, s_ms, rb, cb, n15, q, wcol, t);
#pragma unroll
    for (int m = 0; m < 2; ++m)    // f2 -> s_x cols 128..255 (th = [ax | f2]); f1 dead
#pragma unroll
        for (int ct = 0; ct < 4; ++ct)
#pragma unroll
            for (int r = 0; r < 4; ++r)
                s_x[(rb + m * 16 + q * 4 + r) * XS + 128 + cb + ct * 16 + n15] = f2h(acc[m][ct][r]);
    __syncthreads();
    gemm_f16<8>(s_x, XS, Wp3, rb, cb, n15, q, acc);
    ln_relu(acc, b3, g3, be3, s_red, s_ms, rb, cb, n15, q, wcol, t);

#pragma unroll
    for (int m = 0; m < 2; ++m)
#pragma unroll
        for (int ct = 0; ct < 4; ++ct)
#pragma unroll
            for (int r = 0; r < 4; ++r) {
                int row = rb + m * 16 + q * 4 + r;
                int gr = nb + row;
                int col = cb + ct * 16 + n15;
                if (gr < N) {
                    if (OUT_F16)
                        ((unsigned short*)out)[(size_t)gr * D + col] = f2h(acc[m][ct][r]);
                    else
                        ((float*)out)[(size_t)gr * D + col] = acc[m][ct][r];
                }
            }
}

extern "C" void kernel_launch(void* const* d_in, const int* in_sizes, int n_in,
                              void* d_out, int out_size, void* d_ws, size_t ws_size,
                              hipStream_t stream)
{
    const float* h2   = (const float*)d_in[0];
    const float* ax1  = (const float*)d_in[1];
    const float* ax0  = (const float*)d_in[2];
    const float* bx2  = (const float*)d_in[3];
    const float* bx1  = (const float*)d_in[4];
    const float* brW1 = (const float*)d_in[5];
    const float* brb1 = (const float*)d_in[6];
    const float* brg1 = (const float*)d_in[7];
    const float* brbe1= (const float*)d_in[8];
    const float* brW2 = (const float*)d_in[9];
    const float* brb2 = (const float*)d_in[10];
    const float* brg2 = (const float*)d_in[11];
    const float* brbe2= (const float*)d_in[12];
    const float* sW1  = (const float*)d_in[13];
    const float* sb1  = (const float*)d_in[14];
    const float* sg1  = (const float*)d_in[15];
    const float* sbe1 = (const float*)d_in[16];
    const float* sW2  = (const float*)d_in[17];
    const float* sb2  = (const float*)d_in[18];
    const float* sg2  = (const float*)d_in[19];
    const float* sbe2 = (const float*)d_in[20];
    const float* hW   = (const float*)d_in[21];
    const float* hb   = (const float*)d_in[22];
    const float* hg   = (const float*)d_in[23];
    const float* hbe  = (const float*)d_in[24];
    const int*   src2 = (const int*)d_in[25];
    const int*   dst2 = (const int*)d_in[26];
    const int*   src1 = (const int*)d_in[27];
    const int*   dst1 = (const int*)d_in[28];

    int n2 = in_sizes[0] / D;
    int n1 = in_sizes[1] / D;
    int n0 = in_sizes[2] / D;

    unsigned short* Wp = (unsigned short*)d_ws;   // 262144 fp16 = 512 KB

    const unsigned short* pBr1[2] = { Wp + 0,      Wp + 32768 };
    const unsigned short* pBr2[2] = { Wp + 65536,  Wp + 65536  + 16384 };
    const unsigned short* pS1 [2] = { Wp + 98304,  Wp + 98304  + 32768 };
    const unsigned short* pS2 [2] = { Wp + 163840, Wp + 163840 + 16384 };
    const unsigned short* pH  [2] = { Wp + 196608, Wp + 196608 + 32768 };

    // ---- workspace layout ----
    int nbA = (n1 + 1023) / 1024, nbB = (n0 + 1023) / 1024;
    int AOFFv = nbA * 1024;
    int AN = AOFFv + nbB * 1024;
    auto al = [](size_t x) { return (x + 255) & ~(size_t)255; };
    size_t o = 524288;
    size_t cnt_o  = o; o = al(o + (size_t)AN * 4);
    size_t inc_o  = o; o = al(o + (size_t)AN * 4);
    size_t cur_o  = o; o = al(o + (size_t)AN * 4);
    size_t bsum_o = o; o = al(o + 1024);
    size_t posA_o = o; o = al(o + (size_t)n2 * 4);
    size_t posB_o = o; o = al(o + (size_t)n1 * 4);
    size_t h1_o   = o; o = al(o + (size_t)n1 * 256);
    size_t ebh_o  = o; o = al(o + (size_t)n2 * 256);
    size_t o_csr  = o;
    bool use_csr = (nbA <= 128) && (nbB <= 128) && (ws_size >= o_csr);

    int t2e = (n2 + TE - 1) / TE, t1e = (n1 + TE - 1) / TE;
    int t1n = (n1 + TE - 1) / TE, t0n = (n0 + TE - 1) / TE;

    if (use_csr) {
        int*            cnt    = (int*)((char*)d_ws + cnt_o);
        int*            inc    = (int*)((char*)d_ws + inc_o);
        int*            cursor = (int*)((char*)d_ws + cur_o);
        int*            bsum   = (int*)((char*)d_ws + bsum_o);
        int*            posA   = (int*)((char*)d_ws + posA_o);
        int*            posB   = (int*)((char*)d_ws + posB_o);
        unsigned short* h1     = (unsigned short*)((char*)d_ws + h1_o);
        unsigned short* ebh    = (unsigned short*)((char*)d_ws + ebh_o);

        // ---- single cooperative setup dispatch (pack + zero + hist + scan + pos) ----
        {
            const float *a0 = brW1, *a1 = brW2, *a2 = sW1, *a3 = sW2, *a4 = hW;
            unsigned short* a5 = Wp;
            const int* a6 = dst2; int a7 = n2;
            const int* a8 = dst1; int a9 = n1;
            int *a10 = cnt, *a11 = inc, *a12 = cursor, *a13 = bsum;
            int *a14 = posA, *a15 = posB;
            int a16 = AOFFv, a17 = nbA, a18 = nbB, a19 = AN;
            void* args[] = { &a0, &a1, &a2, &a3, &a4, &a5, &a6, &a7, &a8, &a9,
                             &a10, &a11, &a12, &a13, &a14, &a15, &a16, &a17, &a18, &a19 };
            hipError_t cerr = hipLaunchCooperativeKernel(
                (const void*)csr_coop, dim3(256), dim3(256), args, 0, stream);
            if (cerr != hipSuccess) {
                (void)hipGetLastError();
                // fallback: multi-dispatch setup
                pack_w<<<dim3(1024), dim3(256), 0, stream>>>(brW1, brW2, sW1, sW2, hW, Wp);
                int EG = (n2 + n1 + 255) / 256;
                hipMemsetAsync(cnt, 0, (size_t)AN * 4, stream);
                csr_hist <<<dim3(EG),        dim3(256), 0, stream>>>(dst2, n2, dst1, n1, cnt, AOFFv);
                csr_scanA<<<dim3(nbA + nbB), dim3(256), 0, stream>>>(cnt, inc, bsum, nbA, AOFFv);
                csr_scanB<<<dim3(1),         dim3(256), 0, stream>>>(bsum, nbA, nbB);
                csr_scanC<<<dim3(nbA + nbB), dim3(256), 0, stream>>>(cnt, inc, bsum, cursor, nbA, AOFFv);
                csr_pos  <<<dim3(EG),        dim3(256), 0, stream>>>(dst2, n2, dst1, n1, cursor, posA, posB, AOFFv);
            }
        }

        // ---- iteration 0 (level 2 -> 1) ----
        edge_mlp<false, true><<<dim3(t2e), dim3(256), 0, stream>>>(
            h2, bx2, src2, posA, pBr1[0], pBr2[0],
            brb1, brg1, brbe1, brb2, brg2, brbe2, nullptr, ebh, n2);
        node_mlp<true, true><<<dim3(t1n), dim3(256), 0, stream>>>(
            ax1, nullptr, inc, ebh, pS1[0], pS2[0], pH[0],
            sb1, sg1, sbe1, sb2, sg2, sbe2, hb, hg, hbe, h1, n1);

        // ---- iteration 1 (level 1 -> 0) ----
        edge_mlp<true, true><<<dim3(t1e), dim3(256), 0, stream>>>(
            h1, bx1, src1, posB, pBr1[1], pBr2[1],
            brb1 + D, brg1 + D, brbe1 + D, brb2 + D, brg2 + D, brbe2 + D, nullptr, ebh, n1);
        node_mlp<false, true><<<dim3(t0n), dim3(256), 0, stream>>>(
            ax0, nullptr, inc + AOFFv, ebh, pS1[1], pS2[1], pH[1],
            sb1 + D, sg1 + D, sbe1 + D, sb2 + D, sg2 + D, sbe2 + D,
            hb + D, hg + D, hbe + D, d_out, n0);
    } else {
        // fallback: atomic-aggregation path
        float*          agg = (float*)((char*)d_ws + 524288);
        unsigned short* h1  = (unsigned short*)(agg + (size_t)n1 * D);

        pack_w<<<dim3(1024), dim3(256), 0, stream>>>(brW1, brW2, sW1, sW2, hW, Wp);

        hipMemsetAsync(agg, 0, (size_t)n1 * D * sizeof(float), stream);
        edge_mlp<false, false><<<dim3(t2e), dim3(256), 0, stream>>>(
            h2, bx2, src2, dst2, pBr1[0], pBr2[0],
            brb1, brg1, brbe1, brb2, brg2, brbe2, agg, nullptr, n2);
        node_mlp<true, false><<<dim3(t1n), dim3(256), 0, stream>>>(
            ax1, agg, nullptr, nullptr, pS1[0], pS2[0], pH[0],
            sb1, sg1, sbe1, sb2, sg2, sbe2, hb, hg, hbe, h1, n1);

        hipMemsetAsync(agg, 0, (size_t)n0 * D * sizeof(float), stream);
        edge_mlp<true, false><<<dim3(t1e), dim3(256), 0, stream>>>(
            h1, bx1, src1, dst1, pBr1[1], pBr2[1],
            brb1 + D, brg1 + D, brbe1 + D, brb2 + D, brg2 + D, brbe2 + D, agg, nullptr, n1);
        node_mlp<false, false><<<dim3(t0n), dim3(256), 0, stream>>>(
            ax0, agg, nullptr, nullptr, pS1[1], pS2[1], pH[1],
            sb1 + D, sg1 + D, sbe1 + D, sb2 + D, sg2 + D, sbe2 + D,
            hb + D, hg + D, hbe + D, d_out, n0);
    }
}

// Round 8
// 675.713 us; speedup vs baseline: 1.4415x; 1.2642x over previous
//
#include <hip/hip_runtime.h>

// TPF encoder, MFMA fp16, CSR aggregation (no float atomics), TE=64 tiles.
//
// r7 lesson: cooperative fusion of setup cost +171us (grid.sync drains + 1-block/CU
// pack). Reverted. This round: r3's proven MLP kernels (683us baseline) +
//  - setup dispatches 7 -> 5: cnt-zero fused into pack_w (independent writes),
//    scanB's tiny 256-entry scan replicated into every scanC block.
//  - node_mlp segment-sum unrolled x2 (8 independent 64B loads in flight/iter)
//    to cut the latency exposure of the divergent per-row edge loop.
// Carried: CSR sort-by-dst, packed weights Wp[kb][n][kk], LDS stride 264, s_y
// aliased into s_x upper half, in-register LN, TE=64 wave tile 32x64 (acc[2][4]).

#define D   128
#define TE  64
#define XS  264   // s_x row stride in fp16 elems (s_y lives at +128, same stride)

typedef float  f32x4 __attribute__((ext_vector_type(4)));
typedef _Float16 f16x8 __attribute__((ext_vector_type(8)));

__device__ __forceinline__ unsigned short f2h(float f) {
    union { _Float16 h; unsigned short u; } x;
    x.h = (_Float16)f;
    return x.u;
}

// ---- weight pack + cnt zero (fused; both outputs independent) ----
// Wp[kb*4096 + n*32 + kk] = fp16(W[kb*32+kk][n]) per matrix,level. AN <= 262144.
__global__ __launch_bounds__(256) void pack_zero(
    const float* __restrict__ brW1, const float* __restrict__ brW2,
    const float* __restrict__ sW1,  const float* __restrict__ sW2,
    const float* __restrict__ hW,   unsigned short* __restrict__ Wp,
    int* __restrict__ cnt, int AN)
{
    int p = blockIdx.x * 256 + threadIdx.x;   // 0 .. 262143
    if (p < AN) cnt[p] = 0;
    const float* src; int off, K;
    if (p < 65536)       { src = brW1; off = 0;      K = 256; }
    else if (p < 98304)  { src = brW2; off = 65536;  K = 128; }
    else if (p < 163840) { src = sW1;  off = 98304;  K = 256; }
    else if (p < 196608) { src = sW2;  off = 163840; K = 128; }
    else                 { src = hW;   off = 196608; K = 256; }
    int q = p - off, lvl, r;
    if (K == 256) { lvl = q >> 15; r = q & 32767; }
    else          { lvl = q >> 14; r = q & 16383; }
    int kb = r >> 12, n = (r >> 5) & 127, kk = r & 31;
    Wp[p] = f2h(src[(size_t)lvl * K * 128 + (size_t)(kb * 32 + kk) * 128 + n]);
}

// ================= CSR build (levels fused; A at cnt[0..], B at cnt[AOFF..]) =================

__global__ __launch_bounds__(256) void csr_hist(
    const int* __restrict__ dA, int EA, const int* __restrict__ dB, int EB,
    int* __restrict__ cnt, int AOFFv)
{
    int i = blockIdx.x * 256 + threadIdx.x;
    if (i < EA)               atomicAdd(cnt + dA[i], 1);
    else if (i - EA < EB)     atomicAdd(cnt + AOFFv + dB[i - EA], 1);
}

// per-block (1024 elems) inclusive scan; block sums to bsum (A slots 0.., B slots 128..)
__global__ __launch_bounds__(256) void csr_scanA(
    const int* __restrict__ cnt, int* __restrict__ inc, int* __restrict__ bsum,
    int nbA, int AOFFv)
{
    __shared__ int lds[256];
    int b = blockIdx.x, t = threadIdx.x;
    int lb, ebase, bs;
    if (b < nbA) { lb = b;       ebase = 0;     bs = lb; }
    else         { lb = b - nbA; ebase = AOFFv; bs = 128 + lb; }
    int idx = ebase + lb * 1024 + t * 4;
    int s0 = cnt[idx], s1 = cnt[idx + 1], s2 = cnt[idx + 2], s3 = cnt[idx + 3];
    int p1 = s0 + s1, p2 = p1 + s2, p3 = p2 + s3;
    lds[t] = p3; __syncthreads();
#pragma unroll
    for (int o = 1; o < 256; o <<= 1) {
        int v = (t >= o) ? lds[t - o] : 0;
        __syncthreads();
        lds[t] += v;
        __syncthreads();
    }
    int ex = lds[t] - p3;
    inc[idx] = ex + s0; inc[idx + 1] = ex + p1; inc[idx + 2] = ex + p2; inc[idx + 3] = ex + p3;
    if (t == 255) bsum[bs] = lds[255];
}

// folds old scanB: every block redundantly scans the two bsum regions (<=128 each)
// in LDS, then applies its carry. cursor = exclusive start per node.
__global__ __launch_bounds__(256) void csr_scanC2(
    const int* __restrict__ cnt, int* __restrict__ inc, const int* __restrict__ bsum,
    int* __restrict__ cursor, int nbA, int nbB, int AOFFv)
{
    __shared__ int lds[256];
    int b = blockIdx.x, t = threadIdx.x;
    int seg = t >> 7, i = t & 127;
    int n = seg ? nbB : nbA;
    lds[t] = (i < n) ? bsum[t] : 0;
    __syncthreads();
#pragma unroll
    for (int o = 1; o < 128; o <<= 1) {
        int v = (i >= o) ? lds[t - o] : 0;
        __syncthreads();
        lds[t] += v;
        __syncthreads();
    }
    int lb, ebase, bs;
    if (b < nbA) { lb = b;       ebase = 0;     bs = lb; }
    else         { lb = b - nbA; ebase = AOFFv; bs = 128 + lb; }
    int carry = (lb > 0) ? lds[bs - 1] : 0;
    int idx = ebase + lb * 1024 + t * 4;
#pragma unroll
    for (int j = 0; j < 4; ++j) {
        int v = inc[idx + j] + carry;
        inc[idx + j] = v;
        cursor[idx + j] = v - cnt[idx + j];
    }
}

__global__ __launch_bounds__(256) void csr_pos(
    const int* __restrict__ dA, int EA, const int* __restrict__ dB, int EB,
    int* __restrict__ cursor, int* __restrict__ posA, int* __restrict__ posB, int AOFFv)
{
    int i = blockIdx.x * 256 + threadIdx.x;
    if (i < EA)           posA[i] = atomicAdd(cursor + dA[i], 1);
    else if (i - EA < EB) posB[i - EA] = atomicAdd(cursor + AOFFv + dB[i - EA], 1);
}

// ================= MLP kernels (proven r3 versions) =================

// wave tile: 32 rows (rb + m*16 + q*4 + r) x 64 cols (cb + ct*16 + n15)
template<int KB>
__device__ __forceinline__ void gemm_f16(const unsigned short* s_in, int stride,
    const unsigned short* __restrict__ Wp, int rb, int cb, int n15, int q, f32x4 acc[2][4])
{
    f32x4 zero = {0.f, 0.f, 0.f, 0.f};
#pragma unroll
    for (int m = 0; m < 2; ++m)
#pragma unroll
        for (int ct = 0; ct < 4; ++ct) acc[m][ct] = zero;
#pragma unroll
    for (int kb = 0; kb < KB; ++kb) {
        f16x8 af0 = *(const f16x8*)(s_in + (rb + n15) * stride + kb * 32 + q * 8);
        f16x8 af1 = *(const f16x8*)(s_in + (rb + 16 + n15) * stride + kb * 32 + q * 8);
        const unsigned short* wb = Wp + (size_t)kb * 4096 + q * 8;
#pragma unroll
        for (int ct = 0; ct < 4; ++ct) {
            f16x8 bf = *(const f16x8*)(wb + (cb + ct * 16 + n15) * 32);
            acc[0][ct] = __builtin_amdgcn_mfma_f32_16x16x32_f16(af0, bf, acc[0][ct], 0, 0, 0);
            acc[1][ct] = __builtin_amdgcn_mfma_f32_16x16x32_f16(af1, bf, acc[1][ct], 0, 0, 0);
        }
    }
}

__device__ __forceinline__ void ln_relu(f32x4 acc[2][4],
    const float* __restrict__ b, const float* __restrict__ g, const float* __restrict__ be,
    float* s_red, float* s_ms, int rb, int cb, int n15, int q, int wcol, int t)
{
#pragma unroll
    for (int ct = 0; ct < 4; ++ct) {
        float bb = b[cb + ct * 16 + n15];
#pragma unroll
        for (int m = 0; m < 2; ++m)
#pragma unroll
            for (int r = 0; r < 4; ++r) acc[m][ct][r] += bb;
    }
    float sum[2][4], ss[2][4];
#pragma unroll
    for (int m = 0; m < 2; ++m)
#pragma unroll
        for (int r = 0; r < 4; ++r) {
            sum[m][r] = acc[m][0][r] + acc[m][1][r] + acc[m][2][r] + acc[m][3][r];
            ss[m][r]  = acc[m][0][r]*acc[m][0][r] + acc[m][1][r]*acc[m][1][r]
                      + acc[m][2][r]*acc[m][2][r] + acc[m][3][r]*acc[m][3][r];
        }
#pragma unroll
    for (int off = 1; off < 16; off <<= 1) {
#pragma unroll
        for (int m = 0; m < 2; ++m)
#pragma unroll
            for (int r = 0; r < 4; ++r) {
                sum[m][r] += __shfl_xor(sum[m][r], off, 64);
                ss[m][r]  += __shfl_xor(ss[m][r],  off, 64);
            }
    }
    if (n15 == 0) {
#pragma unroll
        for (int m = 0; m < 2; ++m)
#pragma unroll
            for (int r = 0; r < 4; ++r) {
                int row = rb + m * 16 + q * 4 + r;
                s_red[row * 4 + wcol * 2 + 0] = sum[m][r];
                s_red[row * 4 + wcol * 2 + 1] = ss[m][r];
            }
    }
    __syncthreads();
    if (t < TE) {
        float sm = s_red[t * 4 + 0] + s_red[t * 4 + 2];
        float sq = s_red[t * 4 + 1] + s_red[t * 4 + 3];
        float mean = sm * (1.f / 128.f);
        float var  = sq * (1.f / 128.f) - mean * mean;
        s_ms[t * 2 + 0] = mean;
        s_ms[t * 2 + 1] = rsqrtf(var + 1e-5f);
    }
    __syncthreads();
#pragma unroll
    for (int ct = 0; ct < 4; ++ct) {
        float gg = g[cb + ct * 16 + n15], bb = be[cb + ct * 16 + n15];
#pragma unroll
        for (int m = 0; m < 2; ++m)
#pragma unroll
            for (int r = 0; r < 4; ++r) {
                int row = rb + m * 16 + q * 4 + r;
                float v = (acc[m][ct][r] - s_ms[row * 2 + 0]) * s_ms[row * 2 + 1] * gg + bb;
                acc[m][ct][r] = fmaxf(v, 0.f);
            }
    }
}

// CSR: dstpos = pos[] (sorted slot per edge), output to ebh. Fallback: dstpos = dst[], atomics.
template<bool HBF16, bool CSR>
__global__ __launch_bounds__(256, 4) void edge_mlp(
    const void* __restrict__ hsrc, const float* __restrict__ bond,
    const int* __restrict__ src, const int* __restrict__ dstpos,
    const unsigned short* __restrict__ Wp1, const unsigned short* __restrict__ Wp2,
    const float* __restrict__ b1, const float* __restrict__ g1, const float* __restrict__ be1,
    const float* __restrict__ b2, const float* __restrict__ g2, const float* __restrict__ be2,
    float* __restrict__ agg, unsigned short* __restrict__ ebh, int E)
{
    __shared__ unsigned short s_x[TE * XS];
    __shared__ float s_red[TE * 4];
    __shared__ float s_ms[TE * 2];
    __shared__ int s_src[TE], s_idx[TE];
    unsigned short* s_y = s_x + 128;   // aliased f1 buffer (cols 128..255 dead after GEMM1)

    int t = threadIdx.x, eb = blockIdx.x * TE;
    if (t < TE) {
        int ge = eb + t;
        s_src[t] = (ge < E) ? src[ge] : -1;
        s_idx[t] = (ge < E) ? dstpos[ge] : -1;
    }
    __syncthreads();

    if (HBF16) {
        const unsigned short* hp = (const unsigned short*)hsrc;
        for (int c = t; c < TE * 16; c += 256) {
            int row = c >> 4, k8 = c & 15;
            int s = s_src[row];
            uint4 v = make_uint4(0, 0, 0, 0);
            if (s >= 0) v = *(const uint4*)(hp + (size_t)s * 128 + k8 * 8);
            *(uint4*)(s_x + row * XS + k8 * 8) = v;
        }
    } else {
        const float* hp = (const float*)hsrc;
        for (int c = t; c < TE * 32; c += 256) {
            int row = c >> 5, k4 = c & 31;
            int s = s_src[row];
            float4 v = make_float4(0, 0, 0, 0);
            if (s >= 0) v = *(const float4*)(hp + (size_t)s * 128 + k4 * 4);
            ushort4 o; o.x = f2h(v.x); o.y = f2h(v.y); o.z = f2h(v.z); o.w = f2h(v.w);
            *(ushort4*)(s_x + row * XS + k4 * 4) = o;
        }
    }
    for (int c = t; c < TE * 32; c += 256) {   // bond part (always fp32)
        int row = c >> 5, k4 = c & 31;
        int ge = eb + row;
        float4 v = make_float4(0, 0, 0, 0);
        if (ge < E) v = *(const float4*)(bond + (size_t)ge * 128 + k4 * 4);
        ushort4 o; o.x = f2h(v.x); o.y = f2h(v.y); o.z = f2h(v.z); o.w = f2h(v.w);
        *(ushort4*)(s_x + row * XS + 128 + k4 * 4) = o;
    }
    __syncthreads();

    int l = t & 63, w = t >> 6;
    int n15 = l & 15, q = l >> 4;
    int rb = (w & 1) * 32, cb = (w >> 1) * 64, wcol = w >> 1;

    f32x4 acc[2][4];
    gemm_f16<8>(s_x, XS, Wp1, rb, cb, n15, q, acc);
    ln_relu(acc, b1, g1, be1, s_red, s_ms, rb, cb, n15, q, wcol, t);
#pragma unroll
    for (int m = 0; m < 2; ++m)
#pragma unroll
        for (int ct = 0; ct < 4; ++ct)
#pragma unroll
            for (int r = 0; r < 4; ++r)
                s_y[(rb + m * 16 + q * 4 + r) * XS + cb + ct * 16 + n15] = f2h(acc[m][ct][r]);
    __syncthreads();
    gemm_f16<4>(s_y, XS, Wp2, rb, cb, n15, q, acc);
    ln_relu(acc, b2, g2, be2, s_red, s_ms, rb, cb, n15, q, wcol, t);

    if (CSR) {
#pragma unroll
        for (int m = 0; m < 2; ++m)
#pragma unroll
            for (int ct = 0; ct < 4; ++ct)
#pragma unroll
                for (int r = 0; r < 4; ++r)
                    s_x[(rb + m * 16 + q * 4 + r) * XS + cb + ct * 16 + n15] = f2h(acc[m][ct][r]);
        __syncthreads();
        for (int c = t; c < TE * 16; c += 256) {   // coalesced 256B row stores
            int row = c >> 4, k8 = c & 15;
            int p = s_idx[row];
            if (p >= 0)
                *(uint4*)(ebh + (size_t)p * 128 + k8 * 8) =
                    *(const uint4*)(s_x + row * XS + k8 * 8);
        }
    } else {
#pragma unroll
        for (int m = 0; m < 2; ++m)
#pragma unroll
            for (int ct = 0; ct < 4; ++ct)
#pragma unroll
                for (int r = 0; r < 4; ++r) {
                    int row = rb + m * 16 + q * 4 + r;
                    int gd = s_idx[row];
                    if (gd >= 0)
                        atomicAdd(agg + (size_t)gd * D + cb + ct * 16 + n15, acc[m][ct][r]);
                }
    }
}

// CSR: inc = per-node inclusive edge-count scan; ebh = dst-sorted edge rows.
template<bool OUT_F16, bool CSR>
__global__ __launch_bounds__(256, 4) void node_mlp(
    const float* __restrict__ ax, const float* __restrict__ agg,
    const int* __restrict__ inc, const unsigned short* __restrict__ ebh,
    const unsigned short* __restrict__ Wp1, const unsigned short* __restrict__ Wp2,
    const unsigned short* __restrict__ Wp3,
    const float* __restrict__ b1, const float* __restrict__ g1, const float* __restrict__ be1,
    const float* __restrict__ b2, const float* __restrict__ g2, const float* __restrict__ be2,
    const float* __restrict__ b3, const float* __restrict__ g3, const float* __restrict__ be3,
    void* __restrict__ out, int N)
{
    __shared__ unsigned short s_x[TE * XS];
    __shared__ float s_red[TE * 4];
    __shared__ float s_ms[TE * 2];
    __shared__ int s_beg[TE], s_end[TE];
    unsigned short* s_y = s_x + 128;   // aliased f1 buffer

    int t = threadIdx.x, nb = blockIdx.x * TE;

    if (CSR && t < TE) {
        int gr = nb + t, b0 = 0, e0 = 0;
        if (gr < N) { e0 = inc[gr]; b0 = (gr == 0) ? 0 : inc[gr - 1]; }
        s_beg[t] = b0; s_end[t] = e0;
    }

    for (int c = t; c < TE * 32; c += 256) {   // ax part
        int row = c >> 5, k4 = c & 31;
        int gr = nb + row;
        float4 v = make_float4(0, 0, 0, 0);
        if (gr < N) v = *(const float4*)(ax + (size_t)gr * 128 + k4 * 4);
        ushort4 o; o.x = f2h(v.x); o.y = f2h(v.y); o.z = f2h(v.z); o.w = f2h(v.w);
        *(ushort4*)(s_x + row * XS + k4 * 4) = o;
    }

    if (CSR) {
        __syncthreads();   // s_beg/s_end visible
        // fused segment-sum: 4 threads/row, 32 cols each; unrolled x2 for load ILP
        int r = t >> 2, s4 = t & 3;
        float a[32];
#pragma unroll
        for (int k = 0; k < 32; ++k) a[k] = 0.f;
        int jb = s_beg[r], je = s_end[r];
        int j = jb;
        for (; j + 2 <= je; j += 2) {
            const unsigned short* rp0 = ebh + (size_t)j * 128 + s4 * 32;
            const unsigned short* rp1 = rp0 + 128;
            f16x8 a0 = *(const f16x8*)rp0;
            f16x8 a1 = *(const f16x8*)(rp0 + 8);
            f16x8 a2 = *(const f16x8*)(rp0 + 16);
            f16x8 a3 = *(const f16x8*)(rp0 + 24);
            f16x8 b0 = *(const f16x8*)rp1;
            f16x8 b1v = *(const f16x8*)(rp1 + 8);
            f16x8 b2v = *(const f16x8*)(rp1 + 16);
            f16x8 b3v = *(const f16x8*)(rp1 + 24);
#pragma unroll
            for (int k = 0; k < 8; ++k) {
                a[k]      += (float)a0[k];
                a[8 + k]  += (float)a1[k];
                a[16 + k] += (float)a2[k];
                a[24 + k] += (float)a3[k];
            }
#pragma unroll
            for (int k = 0; k < 8; ++k) {
                a[k]      += (float)b0[k];
                a[8 + k]  += (float)b1v[k];
                a[16 + k] += (float)b2v[k];
                a[24 + k] += (float)b3v[k];
            }
        }
        if (j < je) {
            const unsigned short* rp = ebh + (size_t)j * 128 + s4 * 32;
            f16x8 v0 = *(const f16x8*)rp;
            f16x8 v1 = *(const f16x8*)(rp + 8);
            f16x8 v2 = *(const f16x8*)(rp + 16);
            f16x8 v3 = *(const f16x8*)(rp + 24);
#pragma unroll
            for (int k = 0; k < 8; ++k) {
                a[k]      += (float)v0[k];
                a[8 + k]  += (float)v1[k];
                a[16 + k] += (float)v2[k];
                a[24 + k] += (float)v3[k];
            }
        }
        unsigned short* op = s_x + r * XS + 128 + s4 * 32;
#pragma unroll
        for (int blk = 0; blk < 4; ++blk) {
            f16x8 h;
#pragma unroll
            for (int k = 0; k < 8; ++k) h[k] = (_Float16)a[blk * 8 + k];
            *(f16x8*)(op + blk * 8) = h;
        }
    } else {
        for (int c = t; c < TE * 32; c += 256) {   // agg part (fp32 buffer)
            int row = c >> 5, k4 = c & 31;
            int gr = nb + row;
            float4 v = make_float4(0, 0, 0, 0);
            if (gr < N) v = *(const float4*)(agg + (size_t)gr * 128 + k4 * 4);
            ushort4 o; o.x = f2h(v.x); o.y = f2h(v.y); o.z = f2h(v.z); o.w = f2h(v.w);
            *(ushort4*)(s_x + row * XS + 128 + k4 * 4) = o;
        }
    }
    __syncthreads();

    int l = t & 63, w = t >> 6;
    int n15 = l & 15, q = l >> 4;
    int rb = (w & 1) * 32, cb = (w >> 1) * 64, wcol = w >> 1;

    f32x4 acc[2][4];
    gemm_f16<8>(s_x, XS, Wp1, rb, cb, n15, q, acc);
    ln_relu(acc, b1, g1, be1, s_red, s_ms, rb, cb, n15, q, wcol, t);
#pragma unroll
    for (int m = 0; m < 2; ++m)
#pragma unroll
        for (int ct = 0; ct < 4; ++ct)
#pragma unroll
            for (int r = 0; r < 4; ++r)
                s_y[(rb + m * 16 + q * 4 + r) * XS + cb + ct * 16 + n15] = f2h(acc[m][ct][r]);
    __syncthreads();
    gemm_f16<4>(s_y, XS, Wp2, rb, cb, n15, q, acc);
    ln_relu(acc, b2, g2, be2, s_red, s_ms, rb, cb, n15, q, wcol, t);
#pragma unroll
    for (int m = 0; m < 2; ++m)    // f2 -> s_x cols 128..255 (th = [ax | f2]); f1 dead
#pragma unroll
        for (int ct = 0; ct < 4; ++ct)
#pragma unroll
            for (int r = 0; r < 4; ++r)
                s_x[(rb + m * 16 + q * 4 + r) * XS + 128 + cb + ct * 16 + n15] = f2h(acc[m][ct][r]);
    __syncthreads();
    gemm_f16<8>(s_x, XS, Wp3, rb, cb, n15, q, acc);
    ln_relu(acc, b3, g3, be3, s_red, s_ms, rb, cb, n15, q, wcol, t);

#pragma unroll
    for (int m = 0; m < 2; ++m)
#pragma unroll
        for (int ct = 0; ct < 4; ++ct)
#pragma unroll
            for (int r = 0; r < 4; ++r) {
                int row = rb + m * 16 + q * 4 + r;
                int gr = nb + row;
                int col = cb + ct * 16 + n15;
                if (gr < N) {
                    if (OUT_F16)
                        ((unsigned short*)out)[(size_t)gr * D + col] = f2h(acc[m][ct][r]);
                    else
                        ((float*)out)[(size_t)gr * D + col] = acc[m][ct][r];
                }
            }
}

extern "C" void kernel_launch(void* const* d_in, const int* in_sizes, int n_in,
                              void* d_out, int out_size, void* d_ws, size_t ws_size,
                              hipStream_t stream)
{
    const float* h2   = (const float*)d_in[0];
    const float* ax1  = (const float*)d_in[1];
    const float* ax0  = (const float*)d_in[2];
    const float* bx2  = (const float*)d_in[3];
    const float* bx1  = (const float*)d_in[4];
    const float* brW1 = (const float*)d_in[5];
    const float* brb1 = (const float*)d_in[6];
    const float* brg1 = (const float*)d_in[7];
    const float* brbe1= (const float*)d_in[8];
    const float* brW2 = (const float*)d_in[9];
    const float* brb2 = (const float*)d_in[10];
    const float* brg2 = (const float*)d_in[11];
    const float* brbe2= (const float*)d_in[12];
    const float* sW1  = (const float*)d_in[13];
    const float* sb1  = (const float*)d_in[14];
    const float* sg1  = (const float*)d_in[15];
    const float* sbe1 = (const float*)d_in[16];
    const float* sW2  = (const float*)d_in[17];
    const float* sb2  = (const float*)d_in[18];
    const float* sg2  = (const float*)d_in[19];
    const float* sbe2 = (const float*)d_in[20];
    const float* hW   = (const float*)d_in[21];
    const float* hb   = (const float*)d_in[22];
    const float* hg   = (const float*)d_in[23];
    const float* hbe  = (const float*)d_in[24];
    const int*   src2 = (const int*)d_in[25];
    const int*   dst2 = (const int*)d_in[26];
    const int*   src1 = (const int*)d_in[27];
    const int*   dst1 = (const int*)d_in[28];

    int n2 = in_sizes[0] / D;
    int n1 = in_sizes[1] / D;
    int n0 = in_sizes[2] / D;

    unsigned short* Wp = (unsigned short*)d_ws;   // 262144 fp16 = 512 KB

    const unsigned short* pBr1[2] = { Wp + 0,      Wp + 32768 };
    const unsigned short* pBr2[2] = { Wp + 65536,  Wp + 65536  + 16384 };
    const unsigned short* pS1 [2] = { Wp + 98304,  Wp + 98304  + 32768 };
    const unsigned short* pS2 [2] = { Wp + 163840, Wp + 163840 + 16384 };
    const unsigned short* pH  [2] = { Wp + 196608, Wp + 196608 + 32768 };

    // ---- workspace layout ----
    int nbA = (n1 + 1023) / 1024, nbB = (n0 + 1023) / 1024;
    int AOFFv = nbA * 1024;
    int AN = AOFFv + nbB * 1024;   // <= 262144 when nbA,nbB <= 128
    auto al = [](size_t x) { return (x + 255) & ~(size_t)255; };
    size_t o = 524288;
    size_t cnt_o  = o; o = al(o + (size_t)AN * 4);
    size_t inc_o  = o; o = al(o + (size_t)AN * 4);
    size_t cur_o  = o; o = al(o + (size_t)AN * 4);
    size_t bsum_o = o; o = al(o + 1024);
    size_t posA_o = o; o = al(o + (size_t)n2 * 4);
    size_t posB_o = o; o = al(o + (size_t)n1 * 4);
    size_t h1_o   = o; o = al(o + (size_t)n1 * 256);
    size_t ebh_o  = o; o = al(o + (size_t)n2 * 256);
    size_t o_csr  = o;
    bool use_csr = (nbA <= 128) && (nbB <= 128) && (ws_size >= o_csr);

    int t2e = (n2 + TE - 1) / TE, t1e = (n1 + TE - 1) / TE;
    int t1n = (n1 + TE - 1) / TE, t0n = (n0 + TE - 1) / TE;

    if (use_csr) {
        int*            cnt    = (int*)((char*)d_ws + cnt_o);
        int*            inc    = (int*)((char*)d_ws + inc_o);
        int*            cursor = (int*)((char*)d_ws + cur_o);
        int*            bsum   = (int*)((char*)d_ws + bsum_o);
        int*            posA   = (int*)((char*)d_ws + posA_o);
        int*            posB   = (int*)((char*)d_ws + posB_o);
        unsigned short* h1     = (unsigned short*)((char*)d_ws + h1_o);
        unsigned short* ebh    = (unsigned short*)((char*)d_ws + ebh_o);

        // ---- setup: 5 dispatches (was 7) ----
        int EG = (n2 + n1 + 255) / 256;
        pack_zero<<<dim3(1024), dim3(256), 0, stream>>>(brW1, brW2, sW1, sW2, hW, Wp, cnt, AN);
        csr_hist  <<<dim3(EG),        dim3(256), 0, stream>>>(dst2, n2, dst1, n1, cnt, AOFFv);
        csr_scanA <<<dim3(nbA + nbB), dim3(256), 0, stream>>>(cnt, inc, bsum, nbA, AOFFv);
        csr_scanC2<<<dim3(nbA + nbB), dim3(256), 0, stream>>>(cnt, inc, bsum, cursor, nbA, nbB, AOFFv);
        csr_pos   <<<dim3(EG),        dim3(256), 0, stream>>>(dst2, n2, dst1, n1, cursor, posA, posB, AOFFv);

        // ---- iteration 0 (level 2 -> 1) ----
        edge_mlp<false, true><<<dim3(t2e), dim3(256), 0, stream>>>(
            h2, bx2, src2, posA, pBr1[0], pBr2[0],
            brb1, brg1, brbe1, brb2, brg2, brbe2, nullptr, ebh, n2);
        node_mlp<true, true><<<dim3(t1n), dim3(256), 0, stream>>>(
            ax1, nullptr, inc, ebh, pS1[0], pS2[0], pH[0],
            sb1, sg1, sbe1, sb2, sg2, sbe2, hb, hg, hbe, h1, n1);

        // ---- iteration 1 (level 1 -> 0) ----
        edge_mlp<true, true><<<dim3(t1e), dim3(256), 0, stream>>>(
            h1, bx1, src1, posB, pBr1[1], pBr2[1],
            brb1 + D, brg1 + D, brbe1 + D, brb2 + D, brg2 + D, brbe2 + D, nullptr, ebh, n1);
        node_mlp<false, true><<<dim3(t0n), dim3(256), 0, stream>>>(
            ax0, nullptr, inc + AOFFv, ebh, pS1[1], pS2[1], pH[1],
            sb1 + D, sg1 + D, sbe1 + D, sb2 + D, sg2 + D, sbe2 + D,
            hb + D, hg + D, hbe + D, d_out, n0);
    } else {
        // fallback: atomic-aggregation path
        float*          agg = (float*)((char*)d_ws + 524288);
        unsigned short* h1  = (unsigned short*)(agg + (size_t)n1 * D);

        pack_zero<<<dim3(1024), dim3(256), 0, stream>>>(brW1, brW2, sW1, sW2, hW, Wp, nullptr, 0);

        hipMemsetAsync(agg, 0, (size_t)n1 * D * sizeof(float), stream);
        edge_mlp<false, false><<<dim3(t2e), dim3(256), 0, stream>>>(
            h2, bx2, src2, dst2, pBr1[0], pBr2[0],
            brb1, brg1, brbe1, brb2, brg2, brbe2, agg, nullptr, n2);
        node_mlp<true, false><<<dim3(t1n), dim3(256), 0, stream>>>(
            ax1, agg, nullptr, nullptr, pS1[0], pS2[0], pH[0],
            sb1, sg1, sbe1, sb2, sg2, sbe2, hb, hg, hbe, h1, n1);

        hipMemsetAsync(agg, 0, (size_t)n0 * D * sizeof(float), stream);
        edge_mlp<true, false><<<dim3(t1e), dim3(256), 0, stream>>>(
            h1, bx1, src1, dst1, pBr1[1], pBr2[1],
            brb1 + D, brg1 + D, brbe1 + D, brb2 + D, brg2 + D, brbe2 + D, agg, nullptr, n1);
        node_mlp<false, false><<<dim3(t0n), dim3(256), 0, stream>>>(
            ax0, agg, nullptr, nullptr, pS1[1], pS2[1], pH[1],
            sb1 + D, sg1 + D, sbe1 + D, sb2 + D, sg2 + D, sbe2 + D,
            hb + D, hg + D, hbe + D, d_out, n0);
    }
}